// Round 14
// baseline (950.399 us; speedup 1.0000x reference)
//
#include <hip/hip_runtime.h>
#include <hip/hip_bf16.h>

// MoBA attention, MI355X gfx950 — ROUND 14.
// Controlled experiment: R11 (best, 753us) verbatim + ONLY the R13-validated
// Km-GEMM swap (deletes transf_k + kmean2_k; adds d2bs/gemm4(2,16)/kmcomb).
// wsum keeps R11 structure, writes row-major (GEMM A-operand). One variable.

typedef __attribute__((ext_vector_type(8))) short s8v;   // 8 x bf16 = 16B
typedef __attribute__((ext_vector_type(4))) float f4v;   // mfma accumulator

#define MFMA16(A,B,C) __builtin_amdgcn_mfma_f32_16x16x32_bf16(A,B,C,0,0,0)

__device__ __forceinline__ unsigned short f2b_rne(float f){
  unsigned u = __builtin_bit_cast(unsigned, f);
  u = (u + 0x7FFFu + ((u>>16)&1u)) >> 16;
  return (unsigned short)u;
}
__device__ __forceinline__ float b2f(unsigned short h){
  unsigned u = ((unsigned)h)<<16;
  return __builtin_bit_cast(float, u);
}
__device__ __forceinline__ unsigned pack2(float a, float b){
  return (unsigned)f2b_rne(a) | ((unsigned)f2b_rne(b)<<16);
}
__device__ __forceinline__ void gld16(const void* g, void* l){
  __builtin_amdgcn_global_load_lds((const __attribute__((address_space(1))) void*)g,
                                   (__attribute__((address_space(3))) void*)l, 16, 0, 0);
}

// ---------------- RoPE table: pure f64 phase ----------------
__global__ __launch_bounds__(256) void rtab_k(double2* __restrict__ tab){
  const int i = blockIdx.x*256 + threadIdx.x;      // 2048*32
  if (i >= 2048*32) return;
  const int d2 = i & 31, s = i >> 5;
  const double invf = 1.0 / pow(10000.0, (double)d2 / 32.0);
  const double ph = (double)s * invf;
  tab[i] = make_double2(cos(ph), sin(ph));
}

// ---------------- f32 -> bf16 convert ----------------
__global__ __launch_bounds__(256) void f2b4_k(const float* __restrict__ s,
                                              unsigned short* __restrict__ d, int n4){
  int i = blockIdx.x*256 + threadIdx.x;
  if (i >= n4) return;
  const float4 v = *(const float4*)(s + (size_t)i*4);
  uint2 p; p.x = pack2(v.x, v.y); p.y = pack2(v.z, v.w);
  *(uint2*)(d + (size_t)i*4) = p;
}

// ---------------- f32 -> bf16 split (hi + lo residual) ----------------
__global__ __launch_bounds__(256) void f2bs_k(const float* __restrict__ s,
    unsigned short* __restrict__ hi, unsigned short* __restrict__ lo, int n4){
  int i = blockIdx.x*256 + threadIdx.x;
  if (i >= n4) return;
  const float4 v = *(const float4*)(s + (size_t)i*4);
  unsigned short h0 = f2b_rne(v.x), h1 = f2b_rne(v.y), h2 = f2b_rne(v.z), h3 = f2b_rne(v.w);
  uint2 ph; ph.x = (unsigned)h0 | ((unsigned)h1<<16); ph.y = (unsigned)h2 | ((unsigned)h3<<16);
  uint2 pl; pl.x = pack2(v.x - b2f(h0), v.y - b2f(h1));
  pl.y = pack2(v.z - b2f(h2), v.w - b2f(h3));
  *(uint2*)(hi + (size_t)i*4) = ph;
  *(uint2*)(lo + (size_t)i*4) = pl;
}

// ---------------- f64 -> bf16 split (hi + lo residual) ----------------
__global__ __launch_bounds__(256) void d2bs_k(const double* __restrict__ s,
    unsigned short* __restrict__ hi, unsigned short* __restrict__ lo, int n2){
  const int i = blockIdx.x*256 + threadIdx.x;
  if (i >= n2) return;
  #pragma unroll
  for (int j = 0; j < 2; ++j) {
    const float f = (float)s[(size_t)i*2+j];
    const unsigned short h = f2b_rne(f);
    hi[(size_t)i*2+j] = h;
    lo[(size_t)i*2+j] = f2b_rne(f - b2f(h));
  }
}

// ---------------- weighted chunk sums (f64), R11 structure, row-major out ----------------
// Thread owns hidden-col c; i ascending (order preserved); writes Ac[(n*32+d2)][c].
__global__ __launch_bounds__(128) void wsum_k(const float* __restrict__ hs,
    const double2* __restrict__ tab, double* __restrict__ Ac, double* __restrict__ As){
  const int n = blockIdx.x, cq = blockIdx.y;       // grid (8, 16)
  const int c = cq*128 + threadIdx.x;
  double ac[32] = {}, as_[32] = {};
  for (int i = 0; i < 256; ++i) {
    const int s = n*256 + i;
    const double v = (double)hs[(size_t)s*2048 + c];
    #pragma unroll
    for (int d2 = 0; d2 < 32; ++d2) {
      const double2 t = tab[s*32 + d2];
      ac[d2]  += t.x*v;
      as_[d2] += t.y*v;
    }
  }
  #pragma unroll
  for (int d2 = 0; d2 < 32; ++d2) {
    Ac[(size_t)(n*32 + d2)*2048 + c] = ac[d2]*(1.0/256.0);
    As[(size_t)(n*32 + d2)*2048 + c] = as_[d2]*(1.0/256.0);
  }
}

// ---------------- Km combine from the two split GEMM outputs ----------------
__global__ __launch_bounds__(256) void kmcomb_k(const float* __restrict__ Cc,
    const float* __restrict__ Cs, double* __restrict__ Km){
  const int i = blockIdx.x*256 + threadIdx.x;      // 16384
  const int d = i & 63, h = (i>>6) & 31, n = i >> 11;
  const int d2 = d & 31;
  const size_t row = (size_t)(n*32 + d2)*2048;
  double v;
  if (d < 32) v = (double)Cc[row + h*64 + d2] - (double)Cs[row + h*64 + d2 + 32];
  else        v = (double)Cs[row + h*64 + d2] + (double)Cc[row + h*64 + d2 + 32];
  Km[(size_t)(n*32 + h)*64 + d] = v;
}

// ---------------- gates from f32 q + f64 km; top-4 + margin flag ----------------
__global__ __launch_bounds__(256) void gate_topk_k(const float* __restrict__ Qf,
    const double* __restrict__ Km, unsigned char* __restrict__ Allow,
    unsigned char* __restrict__ Flags){
  const int h = blockIdx.x, c = blockIdx.y, t = threadIdx.x;
  __shared__ double km[512];
  km[t]     = Km[((t>>6)*32 + h)*64 + (t&63)];
  km[t+256] = Km[(((t+256)>>6)*32 + h)*64 + (t&63)];
  __syncthreads();
  const int s = c*256 + t;
  const float* qp = Qf + (size_t)s*2048 + h*64;
  double g[8] = {};
  for (int d = 0; d < 64; ++d) {
    const double qv = (double)qp[d];
    #pragma unroll
    for (int n2 = 0; n2 < 8; ++n2) g[n2] += qv*km[n2*64+d];
  }
  double margin = 1e300;
  if (c >= 4) {
    unsigned pm = 0;
    double v[4];
    for (int rep = 0; rep < 4; ++rep) {
      double best = -1e308; int bi = 0;
      #pragma unroll
      for (int n2 = 0; n2 < 8; ++n2) {
        const bool take = (n2 < c) && !((pm>>n2)&1u) && (g[n2] > best);
        best = take ? g[n2] : best;
        bi   = take ? n2 : bi;
      }
      v[rep] = best; pm |= 1u<<bi;
    }
    margin = v[2] - v[3];
  }
  Flags[h*2048 + s] = (margin < 1e-3) ? 1 : 0;
  #pragma unroll
  for (int n2 = 0; n2 < 8; ++n2) if (n2 > c) g[n2] = -1e300;
  g[c] = 1e300;
  unsigned mask = 0;
  for (int rep = 0; rep < 4; ++rep) {
    double best = -1e308; int bi = 0;
    #pragma unroll
    for (int n2 = 0; n2 < 8; ++n2) {
      const bool take = !((mask>>n2)&1u) && (g[n2] > best);
      best = take ? g[n2] : best;
      bi   = take ? n2 : bi;
    }
    mask |= 1u<<bi;
  }
  Allow[h*2048 + s] = (unsigned char)mask;
}

// ---------------- sparse f64 repair of flagged rows ----------------
__global__ __launch_bounds__(64) void repair_k(
    const float* __restrict__ hs, const float* __restrict__ Wq,
    const double2* __restrict__ tab, const double* __restrict__ Km,
    const unsigned char* __restrict__ Flags, unsigned char* __restrict__ Allow)
{
  const int s = blockIdx.x, d = threadIdx.x;
  __shared__ double qr[64];
  __shared__ double g8[8];
  for (int h = 0; h < 32; ++h) {
    if (!Flags[h*2048 + s]) continue;
    const float* hrow = hs + (size_t)s*2048;
    const float* wrow = Wq + (size_t)(h*64 + d)*2048;
    double a0=0,a1=0,a2=0,a3=0;
    for (int k = 0; k < 2048; k += 4) {
      a0 += (double)hrow[k]  *(double)wrow[k];
      a1 += (double)hrow[k+1]*(double)wrow[k+1];
      a2 += (double)hrow[k+2]*(double)wrow[k+2];
      a3 += (double)hrow[k+3]*(double)wrow[k+3];
    }
    qr[d] = (a0+a1)+(a2+a3);
    __syncthreads();
    const double2 t = tab[s*32 + (d&31)];
    const double rot = (d < 32) ? (qr[d]*t.x - qr[d+32]*t.y)
                                : (qr[d-32]*t.y + qr[d]*t.x);
    __syncthreads();
    qr[d] = rot;
    __syncthreads();
    if (d < 8) {
      double g = 0;
      const double* kmp = Km + (size_t)(d*32 + h)*64;
      for (int dd = 0; dd < 64; ++dd) g += qr[dd]*kmp[dd];
      g8[d] = g;
    }
    __syncthreads();
    if (d == 0) {
      const int c = s >> 8;
      double g[8];
      #pragma unroll
      for (int n2 = 0; n2 < 8; ++n2)
        g[n2] = (n2 > c) ? -1e300 : ((n2 == c) ? 1e300 : g8[n2]);
      unsigned mask = 0;
      for (int rep = 0; rep < 4; ++rep) {
        double best = -1e308; int bi = 0;
        #pragma unroll
        for (int n2 = 0; n2 < 8; ++n2) {
          const bool take = !((mask>>n2)&1u) && (g[n2] > best);
          best = take ? g[n2] : best;
          bi   = take ? n2 : bi;
        }
        mask |= 1u<<bi;
      }
      Allow[h*2048 + s] = (unsigned char)mask;
    }
    __syncthreads();
  }
}

// ---------------- split-bf16 4-term GEMM: C(f32) = (Ah+Al)(Bh+Bl)^T ----------------
__global__ __launch_bounds__(256) void gemm4_bt(
    const unsigned short* __restrict__ Ah, const unsigned short* __restrict__ Al,
    const unsigned short* __restrict__ Bh, const unsigned short* __restrict__ Bl,
    float* __restrict__ C, int M, int N, int K)
{
  alignas(16) __shared__ char SAh[16384];
  alignas(16) __shared__ char SAl[16384];
  alignas(16) __shared__ char SBh[16384];
  alignas(16) __shared__ char SBl[16384];
  const int t = threadIdx.x;
  const int wave = t>>6, lane = t&63, lg = lane>>4, lr = lane&15;
  const int wm = wave >> 1, wn = wave & 1;
  const int m0 = blockIdx.x*128, n0 = blockIdx.y*128;
  const unsigned short* Ahb = Ah + (size_t)m0*K;
  const unsigned short* Alb = Al + (size_t)m0*K;
  const unsigned short* Bhb = Bh + (size_t)n0*K;
  const unsigned short* Blb = Bl + (size_t)n0*K;
  f4v acc[4][4] = {};
  #pragma unroll 1
  for (int kt = 0; kt < K; kt += 64) {
    __syncthreads();
    #pragma unroll
    for (int i = 0; i < 4; ++i) {
      const size_t go = (size_t)(i*32 + (t>>3))*K + kt + (t&7)*8;
      gld16(Ahb + go, SAh + i*4096 + wave*1024);
      gld16(Alb + go, SAl + i*4096 + wave*1024);
      gld16(Bhb + go, SBh + i*4096 + wave*1024);
      gld16(Blb + go, SBl + i*4096 + wave*1024);
    }
    __syncthreads();
    #pragma unroll
    for (int kk = 0; kk < 2; ++kk) {
      s8v ah[4], al[4], bh[4], bl[4];
      #pragma unroll
      for (int i = 0; i < 4; ++i) {
        const int ro = (wm*64 + i*16 + lr)*128 + kk*64 + lg*16;
        ah[i] = *(const s8v*)&SAh[ro];
        al[i] = *(const s8v*)&SAl[ro];
      }
      #pragma unroll
      for (int j = 0; j < 4; ++j) {
        const int ro = (wn*64 + j*16 + lr)*128 + kk*64 + lg*16;
        bh[j] = *(const s8v*)&SBh[ro];
        bl[j] = *(const s8v*)&SBl[ro];
      }
      #pragma unroll
      for (int i = 0; i < 4; ++i)
        #pragma unroll
        for (int j = 0; j < 4; ++j) {
          f4v a = acc[i][j];
          a = MFMA16(ah[i], bh[j], a);
          a = MFMA16(ah[i], bl[j], a);
          a = MFMA16(al[i], bh[j], a);
          a = MFMA16(al[i], bl[j], a);
          acc[i][j] = a;
        }
    }
  }
  #pragma unroll
  for (int i = 0; i < 4; ++i)
    #pragma unroll
    for (int j = 0; j < 4; ++j) {
      const int row = m0 + wm*64 + i*16 + lg*4;
      const int col = n0 + wn*64 + j*16 + lr;
      #pragma unroll
      for (int r = 0; r < 4; ++r)
        C[(size_t)(row+r)*N + col] = acc[i][j][r];
    }
}

// ---------------- bf16 MFMA GEMM: C = A(bf16)·B(bf16)^T ----------------
template<int BM, int BN, int WN, bool OUTBF>
__global__ __launch_bounds__(256) void gemm_bt(
    const unsigned short* __restrict__ A, const unsigned short* __restrict__ B,
    void* __restrict__ C, int M, int N, int K)
{
  alignas(16) __shared__ char AsB[BM*128];
  alignas(16) __shared__ char BsB[BN*128];
  const int t = threadIdx.x;
  const int wave = t>>6, lane = t&63, lg = lane>>4, lr = lane&15;
  const int wm = wave / WN, wn = wave % WN;
  const int m0 = blockIdx.x*BM, n0 = blockIdx.y*BN;
  const unsigned short* Ab = A + (size_t)m0*K;
  const unsigned short* Bb = B + (size_t)n0*K;
  f4v acc[4][4] = {};
  #pragma unroll 1
  for (int kt = 0; kt < K; kt += 64) {
    __syncthreads();
    #pragma unroll
    for (int i = 0; i < BM/32; ++i)
      gld16(Ab + (size_t)(i*32 + (t>>3))*K + kt + (t&7)*8, AsB + i*4096 + wave*1024);
    #pragma unroll
    for (int i = 0; i < BN/32; ++i)
      gld16(Bb + (size_t)(i*32 + (t>>3))*K + kt + (t&7)*8, BsB + i*4096 + wave*1024);
    __syncthreads();
    #pragma unroll
    for (int kk = 0; kk < 2; ++kk) {
      s8v af[4], bfr[4];
      #pragma unroll
      for (int i = 0; i < 4; ++i)
        af[i] = *(const s8v*)&AsB[(wm*64 + i*16 + lr)*128 + kk*64 + lg*16];
      #pragma unroll
      for (int j = 0; j < 4; ++j)
        bfr[j] = *(const s8v*)&BsB[(wn*64 + j*16 + lr)*128 + kk*64 + lg*16];
      #pragma unroll
      for (int i = 0; i < 4; ++i)
        #pragma unroll
        for (int j = 0; j < 4; ++j)
          acc[i][j] = MFMA16(af[i], bfr[j], acc[i][j]);
    }
  }
  #pragma unroll
  for (int i = 0; i < 4; ++i)
    #pragma unroll
    for (int j = 0; j < 4; ++j) {
      const int row = m0 + wm*64 + i*16 + lg*4;
      const int col = n0 + wn*64 + j*16 + lr;
      #pragma unroll
      for (int r = 0; r < 4; ++r) {
        if (OUTBF) ((unsigned short*)C)[(size_t)(row+r)*N + col] = f2b_rne(acc[i][j][r]);
        else       ((float*)C)[(size_t)(row+r)*N + col] = acc[i][j][r];
      }
    }
}

// ---------------- RoPE f32: Q in-place + bf16 out ----------------
__global__ __launch_bounds__(256) void rope32q_k(float* __restrict__ Qf,
    unsigned short* __restrict__ Qb, const double2* __restrict__ tab){
  const int idx = blockIdx.x*256 + threadIdx.x;
  const int d2 = idx & 31, hh = (idx>>5)&31, s = idx>>10;
  const double2 t = tab[s*32 + d2];
  const float cs = (float)t.x, sn = (float)t.y;
  const size_t base = (size_t)s*2048 + hh*64 + d2;
  const float q1 = Qf[base], q2 = Qf[base+32];
  const float o1 = q1*cs - q2*sn, o2 = q1*sn + q2*cs;
  Qf[base] = o1; Qf[base+32] = o2;
  Qb[base] = f2b_rne(o1); Qb[base+32] = f2b_rne(o2);
}

// ---------------- RoPE f32 on K, write bf16 only ----------------
__global__ __launch_bounds__(256) void rope32_k(const float* __restrict__ Kf,
    unsigned short* __restrict__ Kb, const double2* __restrict__ tab){
  const int idx = blockIdx.x*256 + threadIdx.x;
  const int d2 = idx & 31, hh = (idx>>5)&31, s = idx>>10;
  const double2 t = tab[s*32 + d2];
  const float cs = (float)t.x, sn = (float)t.y;
  const size_t base = (size_t)s*2048 + hh*64 + d2;
  const float k1 = Kf[base], k2 = Kf[base+32];
  Kb[base]    = f2b_rne(k1*cs - k2*sn);
  Kb[base+32] = f2b_rne(k1*sn + k2*cs);
}

// ---------------- V transpose: f32 [S][HD] -> bf16 [HD][S] ----------------
__global__ __launch_bounds__(256) void vtrans_k(const float* __restrict__ V,
                                                unsigned short* __restrict__ Vt){
  __shared__ unsigned short tile[64][68];
  const int s0 = blockIdx.x*64, c0 = blockIdx.y*64;
  const int tx = threadIdx.x & 63, ty = threadIdx.x >> 6;
  #pragma unroll
  for (int rr = 0; rr < 16; ++rr) {
    const int r = ty*16 + rr;
    tile[tx][r] = f2b_rne(V[(size_t)(s0+r)*2048 + c0+tx]);
  }
  __syncthreads();
  #pragma unroll
  for (int rr = 0; rr < 16; ++rr) {
    const int cc = ty*16 + rr;
    Vt[(size_t)(c0+cc)*2048 + s0+tx] = tile[cc][tx];
  }
}

// ---------------- MFMA flash attention: 16 q-rows per wave (R11 verbatim) ----------------
__global__ __launch_bounds__(64) void attn_k(
    const unsigned short* __restrict__ Qb, const unsigned short* __restrict__ Kb,
    const unsigned short* __restrict__ Vt, const float* __restrict__ Gf,
    const unsigned char* __restrict__ Allow, const float* __restrict__ Wn,
    float* __restrict__ Of)
{
  const int h = blockIdx.x, c = blockIdx.y, zb = blockIdx.z;
  const int lane = threadIdx.x, lg = lane>>4, lr = lane&15;
  const int qbase = c*256 + zb*16;
  alignas(16) __shared__ char P[2048];

  const size_t qrow = (size_t)(qbase + lr);
  const s8v qf0 = *(const s8v*)&Qb[qrow*2048 + h*64 + lg*8];
  const s8v qf1 = *(const s8v*)&Qb[qrow*2048 + h*64 + 32 + lg*8];
  const unsigned am = Allow[h*2048 + qrow];
  const int q = qbase + lr;
  const int sw = (lr&7)<<4;

  float mx = -1e30f, ls = 0.f;
  f4v ot[4] = {};

  for (int n = 0; n <= c; ++n) {
    if (!__ballot((am>>n)&1u)) continue;
    const int okc = (am>>n)&1;
    #pragma unroll 1
    for (int t4 = 0; t4 < 4; ++t4) {
      const int kb0 = n*256 + t4*64;
      s8v kf[4][2];
      #pragma unroll
      for (int i = 0; i < 4; ++i) {
        const size_t krow = (size_t)(kb0 + i*16 + lr);
        kf[i][0] = *(const s8v*)&Kb[krow*2048 + h*64 + lg*8];
        kf[i][1] = *(const s8v*)&Kb[krow*2048 + h*64 + 32 + lg*8];
      }
      f4v st[4];
      #pragma unroll
      for (int i = 0; i < 4; ++i) {
        f4v zz = {};
        zz = MFMA16(kf[i][0], qf0, zz);
        st[i] = MFMA16(kf[i][1], qf1, zz);
      }
      float cm = -__builtin_inff();
      #pragma unroll
      for (int i = 0; i < 4; ++i)
        #pragma unroll
        for (int r = 0; r < 4; ++r) {
          float v = st[i][r]*0.125f;
          const int key = kb0 + i*16 + lg*4 + r;
          const bool ok = okc && (n != c || key <= q);
          v = ok ? v : -__builtin_inff();
          st[i][r] = v;
          cm = fmaxf(cm, v);
        }
      cm = fmaxf(cm, __shfl_xor(cm, 16));
      cm = fmaxf(cm, __shfl_xor(cm, 32));
      const float nm = fmaxf(mx, cm);
      const float al = __expf(mx - nm);
      mx = nm;
      float ps = 0.f;
      #pragma unroll
      for (int i = 0; i < 4; ++i) {
        const float p0 = __expf(st[i][0]-mx);
        const float p1 = __expf(st[i][1]-mx);
        const float p2 = __expf(st[i][2]-mx);
        const float p3 = __expf(st[i][3]-mx);
        ps += (p0+p1)+(p2+p3);
        uint2 pk; pk.x = pack2(p0,p1); pk.y = pack2(p2,p3);
        *(uint2*)&P[lr*128 + ((i*32 + lg*8) ^ sw)] = pk;
      }
      ps += __shfl_xor(ps, 16);
      ps += __shfl_xor(ps, 32);
      ls = ls*al + ps;
      #pragma unroll
      for (int jd = 0; jd < 4; ++jd) ot[jd] *= al;
      asm volatile("s_waitcnt lgkmcnt(0)" ::: "memory");
      __builtin_amdgcn_sched_barrier(0);
      #pragma unroll
      for (int kk = 0; kk < 2; ++kk) {
        s8v vfr[4];
        #pragma unroll
        for (int jd = 0; jd < 4; ++jd)
          vfr[jd] = *(const s8v*)&Vt[(size_t)(h*64 + jd*16 + lr)*2048 + kb0 + kk*32 + lg*8];
        const s8v pfr = *(const s8v*)&P[lr*128 + ((kk*64 + lg*16) ^ sw)];
        #pragma unroll
        for (int jd = 0; jd < 4; ++jd)
          ot[jd] = MFMA16(vfr[jd], pfr, ot[jd]);
      }
      asm volatile("s_waitcnt lgkmcnt(0)" ::: "memory");
      __builtin_amdgcn_sched_barrier(0);
    }
  }
  const float inv_ = 1.0f/ls;
  float ssum = 0.f;
  #pragma unroll
  for (int jd = 0; jd < 4; ++jd)
    #pragma unroll
    for (int r = 0; r < 4; ++r) {
      const float o = ot[jd][r]*inv_;
      ot[jd][r] = o;
      ssum += o*o;
    }
  ssum += __shfl_xor(ssum, 16);
  ssum += __shfl_xor(ssum, 32);
  const float rmsv = rsqrtf(ssum*(1.0f/64.0f) + 1e-6f);
  #pragma unroll
  for (int jd = 0; jd < 4; ++jd) {
    const float4 w4 = *(const float4*)&Wn[jd*16 + lg*4];
    const float4 g4 = *(const float4*)&Gf[qrow*2048 + h*64 + jd*16 + lg*4];
    float4 o4;
    o4.x = ot[jd][0]*rmsv*w4.x*(1.0f/(1.0f+__expf(-g4.x)));
    o4.y = ot[jd][1]*rmsv*w4.y*(1.0f/(1.0f+__expf(-g4.y)));
    o4.z = ot[jd][2]*rmsv*w4.z*(1.0f/(1.0f+__expf(-g4.z)));
    o4.w = ot[jd][3]*rmsv*w4.w*(1.0f/(1.0f+__expf(-g4.w)));
    *(float4*)&Of[qrow*2048 + h*64 + jd*16 + lg*4] = o4;
  }
}

// ---------------- host launch ----------------
extern "C" void kernel_launch(void* const* d_in, const int* in_sizes, int n_in,
                              void* d_out, int out_size, void* d_ws, size_t ws_size,
                              hipStream_t stream)
{
  const float* hs  = (const float*)d_in[0];
  const float* Wq  = (const float*)d_in[1];
  const float* Wk  = (const float*)d_in[2];
  const float* Wv  = (const float*)d_in[3];
  const float* Wo  = (const float*)d_in[4];
  const float* Wg1 = (const float*)d_in[5];
  const float* Wg2 = (const float*)d_in[6];
  const float* Wn  = (const float*)d_in[7];

  const size_t S2 = (size_t)2048*2048;
  const size_t MB = (size_t)1<<20;
  char* ws = (char*)d_ws;
  // static layout, peak 114MB:
  double2*        tab   = (double2*)       (ws);                   // [0,1)
  unsigned short* Wg1b  = (unsigned short*)(ws + 1*MB);                    // 256KB
  unsigned short* Wg2b  = (unsigned short*)(ws + 1*MB + 262144);          // 256KB
  unsigned short* g1b   = (unsigned short*)(ws + 1*MB + 524288);          // 256KB
  double*         km    = (double*)        (ws + 1*MB + 786432);          // 128KB
  unsigned char*  allow = (unsigned char*) (ws + 1*MB + 917504);          // 64KB
  unsigned char*  flags = (unsigned char*) (ws + 1*MB + 983040);          // 64KB
  unsigned short* hsh   = (unsigned short*)(ws + 2*MB);            // [2,10)
  unsigned short* hsl   = (unsigned short*)(ws + 10*MB);           // [10,18)
  unsigned short* Wqh   = (unsigned short*)(ws + 18*MB);           // [18,26) dead after Q-gemm4
  unsigned short* Wql   = (unsigned short*)(ws + 26*MB);           // [26,34) dead after Q-gemm4
  unsigned short* Wkh   = (unsigned short*)(ws + 34*MB);           // [34,42) dead after Km gemms
  unsigned short* Wkl   = (unsigned short*)(ws + 42*MB);           // [42,50) dead after Km gemms
  unsigned short* Wvb   = (unsigned short*)(ws + 50*MB);           // [50,58) dead after V gemm
  float*          qf    = (float*)         (ws + 58*MB);           // [58,74) dead after gate_topk
  float*          kf    = (float*)         (ws + 74*MB);           // [74,90) dead after rope32
  float*          vf    = (float*)         (ws + 90*MB);           // [90,106) dead after vtrans
  double*         Ac    = (double*)        (ws + 106*MB);          // [106,110) dead after d2bs
  double*         As    = (double*)        (ws + 110*MB);          // [110,114) dead after d2bs
  // phase-2 aliases:
  unsigned short* Ach   = (unsigned short*)(ws + 18*MB);           // dead Wqh [18,19)
  unsigned short* Acl   = (unsigned short*)(ws + 19*MB);           // [19,20)
  unsigned short* Ash   = (unsigned short*)(ws + 20*MB);           // [20,21)
  unsigned short* Asl   = (unsigned short*)(ws + 21*MB);           // [21,22)
  float*          Cc    = (float*)         (ws + 22*MB);           // [22,24)
  float*          Cs    = (float*)         (ws + 24*MB);           // [24,26)
  unsigned short* qb    = (unsigned short*)(ws + 26*MB);           // dead Wql [26,34)
  unsigned short* kb    = (unsigned short*)(ws + 42*MB);           // dead Wkl [42,50)
  unsigned short* vt    = (unsigned short*)(ws + 74*MB);           // dead kf  [74,82)
  unsigned short* ofb   = (unsigned short*)(ws + 82*MB);           // dead kf  [82,90)
  float*          gf    = (float*)         (ws + 90*MB);           // dead vf  [90,106)
  float*          of    = (float*)         (ws + 58*MB);           // dead qf  [58,74)
  unsigned short* Wob   = (unsigned short*)(ws + 106*MB);          // dead Ac/As [106,114)
  (void)ws_size; (void)in_sizes; (void)n_in; (void)out_size;

  rtab_k<<<256,256,0,stream>>>(tab);
  f2bs_k<<<4096,256,0,stream>>>(hs, hsh, hsl, (int)(S2/4));
  f2bs_k<<<4096,256,0,stream>>>(Wq, Wqh, Wql, (int)(S2/4));
  f2bs_k<<<4096,256,0,stream>>>(Wk, Wkh, Wkl, (int)(S2/4));
  f2b4_k<<<4096,256,0,stream>>>(Wv, Wvb, (int)(S2/4));
  f2b4_k<<<128,256,0,stream>>>(Wg1, Wg1b, 64*2048/4);
  f2b4_k<<<128,256,0,stream>>>(Wg2, Wg2b, 2048*64/4);

  // projections (Q f32-exact via 4-term; K,V bf16 — Wkh == f2b4(Wk))
  gemm4_bt<<<dim3(16,16),256,0,stream>>>(hsh, hsl, Wqh, Wql, qf, 2048, 2048, 2048);
  gemm_bt<128,128,2,false><<<dim3(16,16),256,0,stream>>>(hsh, Wkh, kf, 2048, 2048, 2048);
  gemm_bt<128,128,2,false><<<dim3(16,16),256,0,stream>>>(hsh, Wvb, vf, 2048, 2048, 2048);

  // RoPE Q (qb in dead Wql)
  rope32q_k<<<8192,256,0,stream>>>(qf, qb, tab);

  // Km path (R13-validated): f64 wsums -> split-bf16 -> 4-term GEMMs -> combine
  wsum_k<<<dim3(8,16),128,0,stream>>>(hs, tab, Ac, As);
  d2bs_k<<<1024,256,0,stream>>>(Ac, Ach, Acl, 262144);
  d2bs_k<<<1024,256,0,stream>>>(As, Ash, Asl, 262144);
  gemm4_bt<<<dim3(2,16),256,0,stream>>>(Ach, Acl, Wkh, Wkl, Cc, 256, 2048, 2048);
  gemm4_bt<<<dim3(2,16),256,0,stream>>>(Ash, Asl, Wkh, Wkl, Cs, 256, 2048, 2048);
  kmcomb_k<<<64,256,0,stream>>>(Cc, Cs, km);

  // RoPE K (kb in dead Wkl — after Km gemms)
  rope32_k<<<8192,256,0,stream>>>(kf, kb, tab);

  // selection: gates + margin flags + sparse exact repair
  gate_topk_k<<<dim3(32,8),256,0,stream>>>(qf, km, allow, flags);
  repair_k<<<2048,64,0,stream>>>(hs, Wq, tab, km, flags, allow);

  // V transpose and gate activations (gf in dead vf)
  vtrans_k<<<dim3(32,32),256,0,stream>>>(vf, vt);
  gemm_bt<256,64,1,true><<<dim3(8,1),256,0,stream>>>(hsh, Wg1b, g1b, 2048, 64, 2048);
  gemm_bt<128,128,2,false><<<dim3(16,16),256,0,stream>>>(g1b, Wg2b, gf, 2048, 2048, 64);

  // attention (R11 verbatim: 16 q-rows/wave, z=16, f32 gate read, f32 out)
  attn_k<<<dim3(32,8,16),64,0,stream>>>(qb, kb, vt, gf, allow, Wn, of);

  // output projection -> f32 d_out
  f2b4_k<<<4096,256,0,stream>>>(of, ofb, (int)(S2/4));
  f2b4_k<<<4096,256,0,stream>>>(Wo, Wob, (int)(S2/4));
  gemm_bt<128,128,2,false><<<dim3(16,16),256,0,stream>>>(ofb, Wob, d_out, 2048, 2048, 2048);
}

// Round 15
// 850.430 us; speedup vs baseline: 1.1176x; 1.1176x over previous
//
#include <hip/hip_runtime.h>
#include <hip/hip_bf16.h>

// MoBA attention, MI355X gfx950 — ROUND 15.
// R14 with the ACTUAL R11 wsum restored (1024-thr, 4 f64 accums — the R12-R14
// versions carried 32-64 f64 accums/thread -> scratch spills, the real source
// of the +75..+200us regressions). Km-GEMM path retained (R13-validated).

typedef __attribute__((ext_vector_type(8))) short s8v;   // 8 x bf16 = 16B
typedef __attribute__((ext_vector_type(4))) float f4v;   // mfma accumulator

#define MFMA16(A,B,C) __builtin_amdgcn_mfma_f32_16x16x32_bf16(A,B,C,0,0,0)

__device__ __forceinline__ unsigned short f2b_rne(float f){
  unsigned u = __builtin_bit_cast(unsigned, f);
  u = (u + 0x7FFFu + ((u>>16)&1u)) >> 16;
  return (unsigned short)u;
}
__device__ __forceinline__ float b2f(unsigned short h){
  unsigned u = ((unsigned)h)<<16;
  return __builtin_bit_cast(float, u);
}
__device__ __forceinline__ unsigned pack2(float a, float b){
  return (unsigned)f2b_rne(a) | ((unsigned)f2b_rne(b)<<16);
}
__device__ __forceinline__ void gld16(const void* g, void* l){
  __builtin_amdgcn_global_load_lds((const __attribute__((address_space(1))) void*)g,
                                   (__attribute__((address_space(3))) void*)l, 16, 0, 0);
}

// ---------------- RoPE table: pure f64 phase ----------------
__global__ __launch_bounds__(256) void rtab_k(double2* __restrict__ tab){
  const int i = blockIdx.x*256 + threadIdx.x;      // 2048*32
  if (i >= 2048*32) return;
  const int d2 = i & 31, s = i >> 5;
  const double invf = 1.0 / pow(10000.0, (double)d2 / 32.0);
  const double ph = (double)s * invf;
  tab[i] = make_double2(cos(ph), sin(ph));
}

// ---------------- f32 -> bf16 convert ----------------
__global__ __launch_bounds__(256) void f2b4_k(const float* __restrict__ s,
                                              unsigned short* __restrict__ d, int n4){
  int i = blockIdx.x*256 + threadIdx.x;
  if (i >= n4) return;
  const float4 v = *(const float4*)(s + (size_t)i*4);
  uint2 p; p.x = pack2(v.x, v.y); p.y = pack2(v.z, v.w);
  *(uint2*)(d + (size_t)i*4) = p;
}

// ---------------- f32 -> bf16 split (hi + lo residual) ----------------
__global__ __launch_bounds__(256) void f2bs_k(const float* __restrict__ s,
    unsigned short* __restrict__ hi, unsigned short* __restrict__ lo, int n4){
  int i = blockIdx.x*256 + threadIdx.x;
  if (i >= n4) return;
  const float4 v = *(const float4*)(s + (size_t)i*4);
  unsigned short h0 = f2b_rne(v.x), h1 = f2b_rne(v.y), h2 = f2b_rne(v.z), h3 = f2b_rne(v.w);
  uint2 ph; ph.x = (unsigned)h0 | ((unsigned)h1<<16); ph.y = (unsigned)h2 | ((unsigned)h3<<16);
  uint2 pl; pl.x = pack2(v.x - b2f(h0), v.y - b2f(h1));
  pl.y = pack2(v.z - b2f(h2), v.w - b2f(h3));
  *(uint2*)(hi + (size_t)i*4) = ph;
  *(uint2*)(lo + (size_t)i*4) = pl;
}

// ---------------- f64 -> bf16 split (hi + lo residual) ----------------
__global__ __launch_bounds__(256) void d2bs_k(const double* __restrict__ s,
    unsigned short* __restrict__ hi, unsigned short* __restrict__ lo, int n2){
  const int i = blockIdx.x*256 + threadIdx.x;
  if (i >= n2) return;
  #pragma unroll
  for (int j = 0; j < 2; ++j) {
    const float f = (float)s[(size_t)i*2+j];
    const unsigned short h = f2b_rne(f);
    hi[(size_t)i*2+j] = h;
    lo[(size_t)i*2+j] = f2b_rne(f - b2f(h));
  }
}

// ---------------- weighted chunk sums (f64) — R11 verbatim: 4 accums, no spill ----
__global__ __launch_bounds__(1024) void wsum_k(const float* __restrict__ hs,
    const double2* __restrict__ tab, double* __restrict__ Ac, double* __restrict__ As){
  const int n = blockIdx.x, d2 = blockIdx.y, tid = threadIdx.x;   // grid (8,32)
  double ac0=0, as0=0, ac1=0, as1=0;
  for (int i = 0; i < 256; ++i) {
    const int s = n*256 + i;
    const double2 t = tab[s*32 + d2];
    const double v0 = (double)hs[(size_t)s*2048 + tid];
    const double v1 = (double)hs[(size_t)s*2048 + tid + 1024];
    ac0 += t.x*v0; as0 += t.y*v0;
    ac1 += t.x*v1; as1 += t.y*v1;
  }
  const size_t ro = (size_t)(n*32 + d2)*2048;
  Ac[ro + tid]      = ac0*(1.0/256.0);
  Ac[ro + tid+1024] = ac1*(1.0/256.0);
  As[ro + tid]      = as0*(1.0/256.0);
  As[ro + tid+1024] = as1*(1.0/256.0);
}

// ---------------- Km combine from the two split GEMM outputs ----------------
__global__ __launch_bounds__(256) void kmcomb_k(const float* __restrict__ Cc,
    const float* __restrict__ Cs, double* __restrict__ Km){
  const int i = blockIdx.x*256 + threadIdx.x;      // 16384
  const int d = i & 63, h = (i>>6) & 31, n = i >> 11;
  const int d2 = d & 31;
  const size_t row = (size_t)(n*32 + d2)*2048;
  double v;
  if (d < 32) v = (double)Cc[row + h*64 + d2] - (double)Cs[row + h*64 + d2 + 32];
  else        v = (double)Cs[row + h*64 + d2] + (double)Cc[row + h*64 + d2 + 32];
  Km[(size_t)(n*32 + h)*64 + d] = v;
}

// ---------------- gates from f32 q + f64 km; top-4 + margin flag ----------------
__global__ __launch_bounds__(256) void gate_topk_k(const float* __restrict__ Qf,
    const double* __restrict__ Km, unsigned char* __restrict__ Allow,
    unsigned char* __restrict__ Flags){
  const int h = blockIdx.x, c = blockIdx.y, t = threadIdx.x;
  __shared__ double km[512];
  km[t]     = Km[((t>>6)*32 + h)*64 + (t&63)];
  km[t+256] = Km[(((t+256)>>6)*32 + h)*64 + (t&63)];
  __syncthreads();
  const int s = c*256 + t;
  const float* qp = Qf + (size_t)s*2048 + h*64;
  double g[8] = {};
  for (int d = 0; d < 64; ++d) {
    const double qv = (double)qp[d];
    #pragma unroll
    for (int n2 = 0; n2 < 8; ++n2) g[n2] += qv*km[n2*64+d];
  }
  double margin = 1e300;
  if (c >= 4) {
    unsigned pm = 0;
    double v[4];
    for (int rep = 0; rep < 4; ++rep) {
      double best = -1e308; int bi = 0;
      #pragma unroll
      for (int n2 = 0; n2 < 8; ++n2) {
        const bool take = (n2 < c) && !((pm>>n2)&1u) && (g[n2] > best);
        best = take ? g[n2] : best;
        bi   = take ? n2 : bi;
      }
      v[rep] = best; pm |= 1u<<bi;
    }
    margin = v[2] - v[3];
  }
  Flags[h*2048 + s] = (margin < 1e-3) ? 1 : 0;
  #pragma unroll
  for (int n2 = 0; n2 < 8; ++n2) if (n2 > c) g[n2] = -1e300;
  g[c] = 1e300;
  unsigned mask = 0;
  for (int rep = 0; rep < 4; ++rep) {
    double best = -1e308; int bi = 0;
    #pragma unroll
    for (int n2 = 0; n2 < 8; ++n2) {
      const bool take = !((mask>>n2)&1u) && (g[n2] > best);
      best = take ? g[n2] : best;
      bi   = take ? n2 : bi;
    }
    mask |= 1u<<bi;
  }
  Allow[h*2048 + s] = (unsigned char)mask;
}

// ---------------- sparse f64 repair of flagged rows ----------------
__global__ __launch_bounds__(64) void repair_k(
    const float* __restrict__ hs, const float* __restrict__ Wq,
    const double2* __restrict__ tab, const double* __restrict__ Km,
    const unsigned char* __restrict__ Flags, unsigned char* __restrict__ Allow)
{
  const int s = blockIdx.x, d = threadIdx.x;
  __shared__ double qr[64];
  __shared__ double g8[8];
  for (int h = 0; h < 32; ++h) {
    if (!Flags[h*2048 + s]) continue;
    const float* hrow = hs + (size_t)s*2048;
    const float* wrow = Wq + (size_t)(h*64 + d)*2048;
    double a0=0,a1=0,a2=0,a3=0;
    for (int k = 0; k < 2048; k += 4) {
      a0 += (double)hrow[k]  *(double)wrow[k];
      a1 += (double)hrow[k+1]*(double)wrow[k+1];
      a2 += (double)hrow[k+2]*(double)wrow[k+2];
      a3 += (double)hrow[k+3]*(double)wrow[k+3];
    }
    qr[d] = (a0+a1)+(a2+a3);
    __syncthreads();
    const double2 t = tab[s*32 + (d&31)];
    const double rot = (d < 32) ? (qr[d]*t.x - qr[d+32]*t.y)
                                : (qr[d-32]*t.y + qr[d]*t.x);
    __syncthreads();
    qr[d] = rot;
    __syncthreads();
    if (d < 8) {
      double g = 0;
      const double* kmp = Km + (size_t)(d*32 + h)*64;
      for (int dd = 0; dd < 64; ++dd) g += qr[dd]*kmp[dd];
      g8[d] = g;
    }
    __syncthreads();
    if (d == 0) {
      const int c = s >> 8;
      double g[8];
      #pragma unroll
      for (int n2 = 0; n2 < 8; ++n2)
        g[n2] = (n2 > c) ? -1e300 : ((n2 == c) ? 1e300 : g8[n2]);
      unsigned mask = 0;
      for (int rep = 0; rep < 4; ++rep) {
        double best = -1e308; int bi = 0;
        #pragma unroll
        for (int n2 = 0; n2 < 8; ++n2) {
          const bool take = !((mask>>n2)&1u) && (g[n2] > best);
          best = take ? g[n2] : best;
          bi   = take ? n2 : bi;
        }
        mask |= 1u<<bi;
      }
      Allow[h*2048 + s] = (unsigned char)mask;
    }
    __syncthreads();
  }
}

// ---------------- split-bf16 4-term GEMM: C(f32) = (Ah+Al)(Bh+Bl)^T ----------------
__global__ __launch_bounds__(256) void gemm4_bt(
    const unsigned short* __restrict__ Ah, const unsigned short* __restrict__ Al,
    const unsigned short* __restrict__ Bh, const unsigned short* __restrict__ Bl,
    float* __restrict__ C, int M, int N, int K)
{
  alignas(16) __shared__ char SAh[16384];
  alignas(16) __shared__ char SAl[16384];
  alignas(16) __shared__ char SBh[16384];
  alignas(16) __shared__ char SBl[16384];
  const int t = threadIdx.x;
  const int wave = t>>6, lane = t&63, lg = lane>>4, lr = lane&15;
  const int wm = wave >> 1, wn = wave & 1;
  const int m0 = blockIdx.x*128, n0 = blockIdx.y*128;
  const unsigned short* Ahb = Ah + (size_t)m0*K;
  const unsigned short* Alb = Al + (size_t)m0*K;
  const unsigned short* Bhb = Bh + (size_t)n0*K;
  const unsigned short* Blb = Bl + (size_t)n0*K;
  f4v acc[4][4] = {};
  #pragma unroll 1
  for (int kt = 0; kt < K; kt += 64) {
    __syncthreads();
    #pragma unroll
    for (int i = 0; i < 4; ++i) {
      const size_t go = (size_t)(i*32 + (t>>3))*K + kt + (t&7)*8;
      gld16(Ahb + go, SAh + i*4096 + wave*1024);
      gld16(Alb + go, SAl + i*4096 + wave*1024);
      gld16(Bhb + go, SBh + i*4096 + wave*1024);
      gld16(Blb + go, SBl + i*4096 + wave*1024);
    }
    __syncthreads();
    #pragma unroll
    for (int kk = 0; kk < 2; ++kk) {
      s8v ah[4], al[4], bh[4], bl[4];
      #pragma unroll
      for (int i = 0; i < 4; ++i) {
        const int ro = (wm*64 + i*16 + lr)*128 + kk*64 + lg*16;
        ah[i] = *(const s8v*)&SAh[ro];
        al[i] = *(const s8v*)&SAl[ro];
      }
      #pragma unroll
      for (int j = 0; j < 4; ++j) {
        const int ro = (wn*64 + j*16 + lr)*128 + kk*64 + lg*16;
        bh[j] = *(const s8v*)&SBh[ro];
        bl[j] = *(const s8v*)&SBl[ro];
      }
      #pragma unroll
      for (int i = 0; i < 4; ++i)
        #pragma unroll
        for (int j = 0; j < 4; ++j) {
          f4v a = acc[i][j];
          a = MFMA16(ah[i], bh[j], a);
          a = MFMA16(ah[i], bl[j], a);
          a = MFMA16(al[i], bh[j], a);
          a = MFMA16(al[i], bl[j], a);
          acc[i][j] = a;
        }
    }
  }
  #pragma unroll
  for (int i = 0; i < 4; ++i)
    #pragma unroll
    for (int j = 0; j < 4; ++j) {
      const int row = m0 + wm*64 + i*16 + lg*4;
      const int col = n0 + wn*64 + j*16 + lr;
      #pragma unroll
      for (int r = 0; r < 4; ++r)
        C[(size_t)(row+r)*N + col] = acc[i][j][r];
    }
}

// ---------------- bf16 MFMA GEMM: C = A(bf16)·B(bf16)^T ----------------
template<int BM, int BN, int WN, bool OUTBF>
__global__ __launch_bounds__(256) void gemm_bt(
    const unsigned short* __restrict__ A, const unsigned short* __restrict__ B,
    void* __restrict__ C, int M, int N, int K)
{
  alignas(16) __shared__ char AsB[BM*128];
  alignas(16) __shared__ char BsB[BN*128];
  const int t = threadIdx.x;
  const int wave = t>>6, lane = t&63, lg = lane>>4, lr = lane&15;
  const int wm = wave / WN, wn = wave % WN;
  const int m0 = blockIdx.x*BM, n0 = blockIdx.y*BN;
  const unsigned short* Ab = A + (size_t)m0*K;
  const unsigned short* Bb = B + (size_t)n0*K;
  f4v acc[4][4] = {};
  #pragma unroll 1
  for (int kt = 0; kt < K; kt += 64) {
    __syncthreads();
    #pragma unroll
    for (int i = 0; i < BM/32; ++i)
      gld16(Ab + (size_t)(i*32 + (t>>3))*K + kt + (t&7)*8, AsB + i*4096 + wave*1024);
    #pragma unroll
    for (int i = 0; i < BN/32; ++i)
      gld16(Bb + (size_t)(i*32 + (t>>3))*K + kt + (t&7)*8, BsB + i*4096 + wave*1024);
    __syncthreads();
    #pragma unroll
    for (int kk = 0; kk < 2; ++kk) {
      s8v af[4], bfr[4];
      #pragma unroll
      for (int i = 0; i < 4; ++i)
        af[i] = *(const s8v*)&AsB[(wm*64 + i*16 + lr)*128 + kk*64 + lg*16];
      #pragma unroll
      for (int j = 0; j < 4; ++j)
        bfr[j] = *(const s8v*)&BsB[(wn*64 + j*16 + lr)*128 + kk*64 + lg*16];
      #pragma unroll
      for (int i = 0; i < 4; ++i)
        #pragma unroll
        for (int j = 0; j < 4; ++j)
          acc[i][j] = MFMA16(af[i], bfr[j], acc[i][j]);
    }
  }
  #pragma unroll
  for (int i = 0; i < 4; ++i)
    #pragma unroll
    for (int j = 0; j < 4; ++j) {
      const int row = m0 + wm*64 + i*16 + lg*4;
      const int col = n0 + wn*64 + j*16 + lr;
      #pragma unroll
      for (int r = 0; r < 4; ++r) {
        if (OUTBF) ((unsigned short*)C)[(size_t)(row+r)*N + col] = f2b_rne(acc[i][j][r]);
        else       ((float*)C)[(size_t)(row+r)*N + col] = acc[i][j][r];
      }
    }
}

// ---------------- RoPE f32: Q in-place + bf16 out ----------------
__global__ __launch_bounds__(256) void rope32q_k(float* __restrict__ Qf,
    unsigned short* __restrict__ Qb, const double2* __restrict__ tab){
  const int idx = blockIdx.x*256 + threadIdx.x;
  const int d2 = idx & 31, hh = (idx>>5)&31, s = idx>>10;
  const double2 t = tab[s*32 + d2];
  const float cs = (float)t.x, sn = (float)t.y;
  const size_t base = (size_t)s*2048 + hh*64 + d2;
  const float q1 = Qf[base], q2 = Qf[base+32];
  const float o1 = q1*cs - q2*sn, o2 = q1*sn + q2*cs;
  Qf[base] = o1; Qf[base+32] = o2;
  Qb[base] = f2b_rne(o1); Qb[base+32] = f2b_rne(o2);
}

// ---------------- RoPE f32 on K, write bf16 only ----------------
__global__ __launch_bounds__(256) void rope32_k(const float* __restrict__ Kf,
    unsigned short* __restrict__ Kb, const double2* __restrict__ tab){
  const int idx = blockIdx.x*256 + threadIdx.x;
  const int d2 = idx & 31, hh = (idx>>5)&31, s = idx>>10;
  const double2 t = tab[s*32 + d2];
  const float cs = (float)t.x, sn = (float)t.y;
  const size_t base = (size_t)s*2048 + hh*64 + d2;
  const float k1 = Kf[base], k2 = Kf[base+32];
  Kb[base]    = f2b_rne(k1*cs - k2*sn);
  Kb[base+32] = f2b_rne(k1*sn + k2*cs);
}

// ---------------- V transpose: f32 [S][HD] -> bf16 [HD][S] ----------------
__global__ __launch_bounds__(256) void vtrans_k(const float* __restrict__ V,
                                                unsigned short* __restrict__ Vt){
  __shared__ unsigned short tile[64][68];
  const int s0 = blockIdx.x*64, c0 = blockIdx.y*64;
  const int tx = threadIdx.x & 63, ty = threadIdx.x >> 6;
  #pragma unroll
  for (int rr = 0; rr < 16; ++rr) {
    const int r = ty*16 + rr;
    tile[tx][r] = f2b_rne(V[(size_t)(s0+r)*2048 + c0+tx]);
  }
  __syncthreads();
  #pragma unroll
  for (int rr = 0; rr < 16; ++rr) {
    const int cc = ty*16 + rr;
    Vt[(size_t)(c0+cc)*2048 + s0+tx] = tile[cc][tx];
  }
}

// ---------------- MFMA flash attention: 16 q-rows per wave (R11 verbatim) ----------------
__global__ __launch_bounds__(64) void attn_k(
    const unsigned short* __restrict__ Qb, const unsigned short* __restrict__ Kb,
    const unsigned short* __restrict__ Vt, const float* __restrict__ Gf,
    const unsigned char* __restrict__ Allow, const float* __restrict__ Wn,
    float* __restrict__ Of)
{
  const int h = blockIdx.x, c = blockIdx.y, zb = blockIdx.z;
  const int lane = threadIdx.x, lg = lane>>4, lr = lane&15;
  const int qbase = c*256 + zb*16;
  alignas(16) __shared__ char P[2048];

  const size_t qrow = (size_t)(qbase + lr);
  const s8v qf0 = *(const s8v*)&Qb[qrow*2048 + h*64 + lg*8];
  const s8v qf1 = *(const s8v*)&Qb[qrow*2048 + h*64 + 32 + lg*8];
  const unsigned am = Allow[h*2048 + qrow];
  const int q = qbase + lr;
  const int sw = (lr&7)<<4;

  float mx = -1e30f, ls = 0.f;
  f4v ot[4] = {};

  for (int n = 0; n <= c; ++n) {
    if (!__ballot((am>>n)&1u)) continue;
    const int okc = (am>>n)&1;
    #pragma unroll 1
    for (int t4 = 0; t4 < 4; ++t4) {
      const int kb0 = n*256 + t4*64;
      s8v kf[4][2];
      #pragma unroll
      for (int i = 0; i < 4; ++i) {
        const size_t krow = (size_t)(kb0 + i*16 + lr);
        kf[i][0] = *(const s8v*)&Kb[krow*2048 + h*64 + lg*8];
        kf[i][1] = *(const s8v*)&Kb[krow*2048 + h*64 + 32 + lg*8];
      }
      f4v st[4];
      #pragma unroll
      for (int i = 0; i < 4; ++i) {
        f4v zz = {};
        zz = MFMA16(kf[i][0], qf0, zz);
        st[i] = MFMA16(kf[i][1], qf1, zz);
      }
      float cm = -__builtin_inff();
      #pragma unroll
      for (int i = 0; i < 4; ++i)
        #pragma unroll
        for (int r = 0; r < 4; ++r) {
          float v = st[i][r]*0.125f;
          const int key = kb0 + i*16 + lg*4 + r;
          const bool ok = okc && (n != c || key <= q);
          v = ok ? v : -__builtin_inff();
          st[i][r] = v;
          cm = fmaxf(cm, v);
        }
      cm = fmaxf(cm, __shfl_xor(cm, 16));
      cm = fmaxf(cm, __shfl_xor(cm, 32));
      const float nm = fmaxf(mx, cm);
      const float al = __expf(mx - nm);
      mx = nm;
      float ps = 0.f;
      #pragma unroll
      for (int i = 0; i < 4; ++i) {
        const float p0 = __expf(st[i][0]-mx);
        const float p1 = __expf(st[i][1]-mx);
        const float p2 = __expf(st[i][2]-mx);
        const float p3 = __expf(st[i][3]-mx);
        ps += (p0+p1)+(p2+p3);
        uint2 pk; pk.x = pack2(p0,p1); pk.y = pack2(p2,p3);
        *(uint2*)&P[lr*128 + ((i*32 + lg*8) ^ sw)] = pk;
      }
      ps += __shfl_xor(ps, 16);
      ps += __shfl_xor(ps, 32);
      ls = ls*al + ps;
      #pragma unroll
      for (int jd = 0; jd < 4; ++jd) ot[jd] *= al;
      asm volatile("s_waitcnt lgkmcnt(0)" ::: "memory");
      __builtin_amdgcn_sched_barrier(0);
      #pragma unroll
      for (int kk = 0; kk < 2; ++kk) {
        s8v vfr[4];
        #pragma unroll
        for (int jd = 0; jd < 4; ++jd)
          vfr[jd] = *(const s8v*)&Vt[(size_t)(h*64 + jd*16 + lr)*2048 + kb0 + kk*32 + lg*8];
        const s8v pfr = *(const s8v*)&P[lr*128 + ((kk*64 + lg*16) ^ sw)];
        #pragma unroll
        for (int jd = 0; jd < 4; ++jd)
          ot[jd] = MFMA16(vfr[jd], pfr, ot[jd]);
      }
      asm volatile("s_waitcnt lgkmcnt(0)" ::: "memory");
      __builtin_amdgcn_sched_barrier(0);
    }
  }
  const float inv_ = 1.0f/ls;
  float ssum = 0.f;
  #pragma unroll
  for (int jd = 0; jd < 4; ++jd)
    #pragma unroll
    for (int r = 0; r < 4; ++r) {
      const float o = ot[jd][r]*inv_;
      ot[jd][r] = o;
      ssum += o*o;
    }
  ssum += __shfl_xor(ssum, 16);
  ssum += __shfl_xor(ssum, 32);
  const float rmsv = rsqrtf(ssum*(1.0f/64.0f) + 1e-6f);
  #pragma unroll
  for (int jd = 0; jd < 4; ++jd) {
    const float4 w4 = *(const float4*)&Wn[jd*16 + lg*4];
    const float4 g4 = *(const float4*)&Gf[qrow*2048 + h*64 + jd*16 + lg*4];
    float4 o4;
    o4.x = ot[jd][0]*rmsv*w4.x*(1.0f/(1.0f+__expf(-g4.x)));
    o4.y = ot[jd][1]*rmsv*w4.y*(1.0f/(1.0f+__expf(-g4.y)));
    o4.z = ot[jd][2]*rmsv*w4.z*(1.0f/(1.0f+__expf(-g4.z)));
    o4.w = ot[jd][3]*rmsv*w4.w*(1.0f/(1.0f+__expf(-g4.w)));
    *(float4*)&Of[qrow*2048 + h*64 + jd*16 + lg*4] = o4;
  }
}

// ---------------- host launch ----------------
extern "C" void kernel_launch(void* const* d_in, const int* in_sizes, int n_in,
                              void* d_out, int out_size, void* d_ws, size_t ws_size,
                              hipStream_t stream)
{
  const float* hs  = (const float*)d_in[0];
  const float* Wq  = (const float*)d_in[1];
  const float* Wk  = (const float*)d_in[2];
  const float* Wv  = (const float*)d_in[3];
  const float* Wo  = (const float*)d_in[4];
  const float* Wg1 = (const float*)d_in[5];
  const float* Wg2 = (const float*)d_in[6];
  const float* Wn  = (const float*)d_in[7];

  const size_t S2 = (size_t)2048*2048;
  const size_t MB = (size_t)1<<20;
  char* ws = (char*)d_ws;
  // static layout, peak 114MB:
  double2*        tab   = (double2*)       (ws);                   // [0,1)
  unsigned short* Wg1b  = (unsigned short*)(ws + 1*MB);                    // 256KB
  unsigned short* Wg2b  = (unsigned short*)(ws + 1*MB + 262144);          // 256KB
  unsigned short* g1b   = (unsigned short*)(ws + 1*MB + 524288);          // 256KB
  double*         km    = (double*)        (ws + 1*MB + 786432);          // 128KB
  unsigned char*  allow = (unsigned char*) (ws + 1*MB + 917504);          // 64KB
  unsigned char*  flags = (unsigned char*) (ws + 1*MB + 983040);          // 64KB
  unsigned short* hsh   = (unsigned short*)(ws + 2*MB);            // [2,10)
  unsigned short* hsl   = (unsigned short*)(ws + 10*MB);           // [10,18)
  unsigned short* Wqh   = (unsigned short*)(ws + 18*MB);           // [18,26) dead after Q-gemm4
  unsigned short* Wql   = (unsigned short*)(ws + 26*MB);           // [26,34) dead after Q-gemm4
  unsigned short* Wkh   = (unsigned short*)(ws + 34*MB);           // [34,42) dead after Km gemms
  unsigned short* Wkl   = (unsigned short*)(ws + 42*MB);           // [42,50) dead after Km gemms
  unsigned short* Wvb   = (unsigned short*)(ws + 50*MB);           // [50,58) dead after V gemm
  float*          qf    = (float*)         (ws + 58*MB);           // [58,74) dead after gate_topk
  float*          kf    = (float*)         (ws + 74*MB);           // [74,90) dead after rope32
  float*          vf    = (float*)         (ws + 90*MB);           // [90,106) dead after vtrans
  double*         Ac    = (double*)        (ws + 106*MB);          // [106,110) dead after d2bs
  double*         As    = (double*)        (ws + 110*MB);          // [110,114) dead after d2bs
  // phase-2 aliases:
  unsigned short* Ach   = (unsigned short*)(ws + 18*MB);           // dead Wqh [18,19)
  unsigned short* Acl   = (unsigned short*)(ws + 19*MB);           // [19,20)
  unsigned short* Ash   = (unsigned short*)(ws + 20*MB);           // [20,21)
  unsigned short* Asl   = (unsigned short*)(ws + 21*MB);           // [21,22)
  float*          Cc    = (float*)         (ws + 22*MB);           // [22,24)
  float*          Cs    = (float*)         (ws + 24*MB);           // [24,26)
  unsigned short* qb    = (unsigned short*)(ws + 26*MB);           // dead Wql [26,34)
  unsigned short* kb    = (unsigned short*)(ws + 42*MB);           // dead Wkl [42,50)
  unsigned short* vt    = (unsigned short*)(ws + 74*MB);           // dead kf  [74,82)
  unsigned short* ofb   = (unsigned short*)(ws + 82*MB);           // dead kf  [82,90)
  float*          gf    = (float*)         (ws + 90*MB);           // dead vf  [90,106)
  float*          of    = (float*)         (ws + 58*MB);           // dead qf  [58,74)
  unsigned short* Wob   = (unsigned short*)(ws + 106*MB);          // dead Ac/As [106,114)
  (void)ws_size; (void)in_sizes; (void)n_in; (void)out_size;

  rtab_k<<<256,256,0,stream>>>(tab);
  f2bs_k<<<4096,256,0,stream>>>(hs, hsh, hsl, (int)(S2/4));
  f2bs_k<<<4096,256,0,stream>>>(Wq, Wqh, Wql, (int)(S2/4));
  f2bs_k<<<4096,256,0,stream>>>(Wk, Wkh, Wkl, (int)(S2/4));
  f2b4_k<<<4096,256,0,stream>>>(Wv, Wvb, (int)(S2/4));
  f2b4_k<<<128,256,0,stream>>>(Wg1, Wg1b, 64*2048/4);
  f2b4_k<<<128,256,0,stream>>>(Wg2, Wg2b, 2048*64/4);

  // projections (Q f32-exact via 4-term; K,V bf16 — Wkh == f2b4(Wk))
  gemm4_bt<<<dim3(16,16),256,0,stream>>>(hsh, hsl, Wqh, Wql, qf, 2048, 2048, 2048);
  gemm_bt<128,128,2,false><<<dim3(16,16),256,0,stream>>>(hsh, Wkh, kf, 2048, 2048, 2048);
  gemm_bt<128,128,2,false><<<dim3(16,16),256,0,stream>>>(hsh, Wvb, vf, 2048, 2048, 2048);

  // RoPE Q (qb in dead Wql)
  rope32q_k<<<8192,256,0,stream>>>(qf, qb, tab);

  // Km path: R11 wsum (clean) -> split-bf16 -> 4-term GEMMs -> combine
  wsum_k<<<dim3(8,32),1024,0,stream>>>(hs, tab, Ac, As);
  d2bs_k<<<1024,256,0,stream>>>(Ac, Ach, Acl, 262144);
  d2bs_k<<<1024,256,0,stream>>>(As, Ash, Asl, 262144);
  gemm4_bt<<<dim3(2,16),256,0,stream>>>(Ach, Acl, Wkh, Wkl, Cc, 256, 2048, 2048);
  gemm4_bt<<<dim3(2,16),256,0,stream>>>(Ash, Asl, Wkh, Wkl, Cs, 256, 2048, 2048);
  kmcomb_k<<<64,256,0,stream>>>(Cc, Cs, km);

  // RoPE K (kb in dead Wkl — after Km gemms)
  rope32_k<<<8192,256,0,stream>>>(kf, kb, tab);

  // selection: gates + margin flags + sparse exact repair
  gate_topk_k<<<dim3(32,8),256,0,stream>>>(qf, km, allow, flags);
  repair_k<<<2048,64,0,stream>>>(hs, Wq, tab, km, flags, allow);

  // V transpose and gate activations (gf in dead vf)
  vtrans_k<<<dim3(32,32),256,0,stream>>>(vf, vt);
  gemm_bt<256,64,1,true><<<dim3(8,1),256,0,stream>>>(hsh, Wg1b, g1b, 2048, 64, 2048);
  gemm_bt<128,128,2,false><<<dim3(16,16),256,0,stream>>>(g1b, Wg2b, gf, 2048, 2048, 64);

  // attention (R11 verbatim: 16 q-rows/wave, z=16, f32 gate read, f32 out)
  attn_k<<<dim3(32,8,16),64,0,stream>>>(qb, kb, vt, gf, allow, Wn, of);

  // output projection -> f32 d_out
  f2b4_k<<<4096,256,0,stream>>>(of, ofb, (int)(S2/4));
  f2b4_k<<<4096,256,0,stream>>>(Wo, Wob, (int)(S2/4));
  gemm_bt<128,128,2,false><<<dim3(16,16),256,0,stream>>>(ofb, Wob, d_out, 2048, 2048, 2048);
}

// Round 16
// 837.134 us; speedup vs baseline: 1.1353x; 1.0159x over previous
//
#include <hip/hip_runtime.h>
#include <hip/hip_bf16.h>

// MoBA attention, MI355X gfx950 — ROUND 16.
// R15 + ONE change: attn_k software-pipelined. Double-buffered K prefetch
// (kA/kB, full t4 unroll for static indexing), V loads hoisted above the
// softmax/sched_barrier, cross-chunk prefetch via active-chunk bitmask.
// Math bit-identical to R15's attn. Everything else untouched.

typedef __attribute__((ext_vector_type(8))) short s8v;   // 8 x bf16 = 16B
typedef __attribute__((ext_vector_type(4))) float f4v;   // mfma accumulator

#define MFMA16(A,B,C) __builtin_amdgcn_mfma_f32_16x16x32_bf16(A,B,C,0,0,0)

__device__ __forceinline__ unsigned short f2b_rne(float f){
  unsigned u = __builtin_bit_cast(unsigned, f);
  u = (u + 0x7FFFu + ((u>>16)&1u)) >> 16;
  return (unsigned short)u;
}
__device__ __forceinline__ float b2f(unsigned short h){
  unsigned u = ((unsigned)h)<<16;
  return __builtin_bit_cast(float, u);
}
__device__ __forceinline__ unsigned pack2(float a, float b){
  return (unsigned)f2b_rne(a) | ((unsigned)f2b_rne(b)<<16);
}
__device__ __forceinline__ void gld16(const void* g, void* l){
  __builtin_amdgcn_global_load_lds((const __attribute__((address_space(1))) void*)g,
                                   (__attribute__((address_space(3))) void*)l, 16, 0, 0);
}

// ---------------- RoPE table: pure f64 phase ----------------
__global__ __launch_bounds__(256) void rtab_k(double2* __restrict__ tab){
  const int i = blockIdx.x*256 + threadIdx.x;      // 2048*32
  if (i >= 2048*32) return;
  const int d2 = i & 31, s = i >> 5;
  const double invf = 1.0 / pow(10000.0, (double)d2 / 32.0);
  const double ph = (double)s * invf;
  tab[i] = make_double2(cos(ph), sin(ph));
}

// ---------------- f32 -> bf16 convert ----------------
__global__ __launch_bounds__(256) void f2b4_k(const float* __restrict__ s,
                                              unsigned short* __restrict__ d, int n4){
  int i = blockIdx.x*256 + threadIdx.x;
  if (i >= n4) return;
  const float4 v = *(const float4*)(s + (size_t)i*4);
  uint2 p; p.x = pack2(v.x, v.y); p.y = pack2(v.z, v.w);
  *(uint2*)(d + (size_t)i*4) = p;
}

// ---------------- f32 -> bf16 split (hi + lo residual) ----------------
__global__ __launch_bounds__(256) void f2bs_k(const float* __restrict__ s,
    unsigned short* __restrict__ hi, unsigned short* __restrict__ lo, int n4){
  int i = blockIdx.x*256 + threadIdx.x;
  if (i >= n4) return;
  const float4 v = *(const float4*)(s + (size_t)i*4);
  unsigned short h0 = f2b_rne(v.x), h1 = f2b_rne(v.y), h2 = f2b_rne(v.z), h3 = f2b_rne(v.w);
  uint2 ph; ph.x = (unsigned)h0 | ((unsigned)h1<<16); ph.y = (unsigned)h2 | ((unsigned)h3<<16);
  uint2 pl; pl.x = pack2(v.x - b2f(h0), v.y - b2f(h1));
  pl.y = pack2(v.z - b2f(h2), v.w - b2f(h3));
  *(uint2*)(hi + (size_t)i*4) = ph;
  *(uint2*)(lo + (size_t)i*4) = pl;
}

// ---------------- f64 -> bf16 split (hi + lo residual) ----------------
__global__ __launch_bounds__(256) void d2bs_k(const double* __restrict__ s,
    unsigned short* __restrict__ hi, unsigned short* __restrict__ lo, int n2){
  const int i = blockIdx.x*256 + threadIdx.x;
  if (i >= n2) return;
  #pragma unroll
  for (int j = 0; j < 2; ++j) {
    const float f = (float)s[(size_t)i*2+j];
    const unsigned short h = f2b_rne(f);
    hi[(size_t)i*2+j] = h;
    lo[(size_t)i*2+j] = f2b_rne(f - b2f(h));
  }
}

// ---------------- weighted chunk sums (f64): 4 accums, no spill ----------------
__global__ __launch_bounds__(1024) void wsum_k(const float* __restrict__ hs,
    const double2* __restrict__ tab, double* __restrict__ Ac, double* __restrict__ As){
  const int n = blockIdx.x, d2 = blockIdx.y, tid = threadIdx.x;   // grid (8,32)
  double ac0=0, as0=0, ac1=0, as1=0;
  for (int i = 0; i < 256; ++i) {
    const int s = n*256 + i;
    const double2 t = tab[s*32 + d2];
    const double v0 = (double)hs[(size_t)s*2048 + tid];
    const double v1 = (double)hs[(size_t)s*2048 + tid + 1024];
    ac0 += t.x*v0; as0 += t.y*v0;
    ac1 += t.x*v1; as1 += t.y*v1;
  }
  const size_t ro = (size_t)(n*32 + d2)*2048;
  Ac[ro + tid]      = ac0*(1.0/256.0);
  Ac[ro + tid+1024] = ac1*(1.0/256.0);
  As[ro + tid]      = as0*(1.0/256.0);
  As[ro + tid+1024] = as1*(1.0/256.0);
}

// ---------------- Km combine from the two split GEMM outputs ----------------
__global__ __launch_bounds__(256) void kmcomb_k(const float* __restrict__ Cc,
    const float* __restrict__ Cs, double* __restrict__ Km){
  const int i = blockIdx.x*256 + threadIdx.x;      // 16384
  const int d = i & 63, h = (i>>6) & 31, n = i >> 11;
  const int d2 = d & 31;
  const size_t row = (size_t)(n*32 + d2)*2048;
  double v;
  if (d < 32) v = (double)Cc[row + h*64 + d2] - (double)Cs[row + h*64 + d2 + 32];
  else        v = (double)Cs[row + h*64 + d2] + (double)Cc[row + h*64 + d2 + 32];
  Km[(size_t)(n*32 + h)*64 + d] = v;
}

// ---------------- gates from f32 q + f64 km; top-4 + margin flag ----------------
__global__ __launch_bounds__(256) void gate_topk_k(const float* __restrict__ Qf,
    const double* __restrict__ Km, unsigned char* __restrict__ Allow,
    unsigned char* __restrict__ Flags){
  const int h = blockIdx.x, c = blockIdx.y, t = threadIdx.x;
  __shared__ double km[512];
  km[t]     = Km[((t>>6)*32 + h)*64 + (t&63)];
  km[t+256] = Km[(((t+256)>>6)*32 + h)*64 + (t&63)];
  __syncthreads();
  const int s = c*256 + t;
  const float* qp = Qf + (size_t)s*2048 + h*64;
  double g[8] = {};
  for (int d = 0; d < 64; ++d) {
    const double qv = (double)qp[d];
    #pragma unroll
    for (int n2 = 0; n2 < 8; ++n2) g[n2] += qv*km[n2*64+d];
  }
  double margin = 1e300;
  if (c >= 4) {
    unsigned pm = 0;
    double v[4];
    for (int rep = 0; rep < 4; ++rep) {
      double best = -1e308; int bi = 0;
      #pragma unroll
      for (int n2 = 0; n2 < 8; ++n2) {
        const bool take = (n2 < c) && !((pm>>n2)&1u) && (g[n2] > best);
        best = take ? g[n2] : best;
        bi   = take ? n2 : bi;
      }
      v[rep] = best; pm |= 1u<<bi;
    }
    margin = v[2] - v[3];
  }
  Flags[h*2048 + s] = (margin < 1e-3) ? 1 : 0;
  #pragma unroll
  for (int n2 = 0; n2 < 8; ++n2) if (n2 > c) g[n2] = -1e300;
  g[c] = 1e300;
  unsigned mask = 0;
  for (int rep = 0; rep < 4; ++rep) {
    double best = -1e308; int bi = 0;
    #pragma unroll
    for (int n2 = 0; n2 < 8; ++n2) {
      const bool take = !((mask>>n2)&1u) && (g[n2] > best);
      best = take ? g[n2] : best;
      bi   = take ? n2 : bi;
    }
    mask |= 1u<<bi;
  }
  Allow[h*2048 + s] = (unsigned char)mask;
}

// ---------------- sparse f64 repair of flagged rows ----------------
__global__ __launch_bounds__(64) void repair_k(
    const float* __restrict__ hs, const float* __restrict__ Wq,
    const double2* __restrict__ tab, const double* __restrict__ Km,
    const unsigned char* __restrict__ Flags, unsigned char* __restrict__ Allow)
{
  const int s = blockIdx.x, d = threadIdx.x;
  __shared__ double qr[64];
  __shared__ double g8[8];
  for (int h = 0; h < 32; ++h) {
    if (!Flags[h*2048 + s]) continue;
    const float* hrow = hs + (size_t)s*2048;
    const float* wrow = Wq + (size_t)(h*64 + d)*2048;
    double a0=0,a1=0,a2=0,a3=0;
    for (int k = 0; k < 2048; k += 4) {
      a0 += (double)hrow[k]  *(double)wrow[k];
      a1 += (double)hrow[k+1]*(double)wrow[k+1];
      a2 += (double)hrow[k+2]*(double)wrow[k+2];
      a3 += (double)hrow[k+3]*(double)wrow[k+3];
    }
    qr[d] = (a0+a1)+(a2+a3);
    __syncthreads();
    const double2 t = tab[s*32 + (d&31)];
    const double rot = (d < 32) ? (qr[d]*t.x - qr[d+32]*t.y)
                                : (qr[d-32]*t.y + qr[d]*t.x);
    __syncthreads();
    qr[d] = rot;
    __syncthreads();
    if (d < 8) {
      double g = 0;
      const double* kmp = Km + (size_t)(d*32 + h)*64;
      for (int dd = 0; dd < 64; ++dd) g += qr[dd]*kmp[dd];
      g8[d] = g;
    }
    __syncthreads();
    if (d == 0) {
      const int c = s >> 8;
      double g[8];
      #pragma unroll
      for (int n2 = 0; n2 < 8; ++n2)
        g[n2] = (n2 > c) ? -1e300 : ((n2 == c) ? 1e300 : g8[n2]);
      unsigned mask = 0;
      for (int rep = 0; rep < 4; ++rep) {
        double best = -1e308; int bi = 0;
        #pragma unroll
        for (int n2 = 0; n2 < 8; ++n2) {
          const bool take = !((mask>>n2)&1u) && (g[n2] > best);
          best = take ? g[n2] : best;
          bi   = take ? n2 : bi;
        }
        mask |= 1u<<bi;
      }
      Allow[h*2048 + s] = (unsigned char)mask;
    }
    __syncthreads();
  }
}

// ---------------- split-bf16 4-term GEMM: C(f32) = (Ah+Al)(Bh+Bl)^T ----------------
__global__ __launch_bounds__(256) void gemm4_bt(
    const unsigned short* __restrict__ Ah, const unsigned short* __restrict__ Al,
    const unsigned short* __restrict__ Bh, const unsigned short* __restrict__ Bl,
    float* __restrict__ C, int M, int N, int K)
{
  alignas(16) __shared__ char SAh[16384];
  alignas(16) __shared__ char SAl[16384];
  alignas(16) __shared__ char SBh[16384];
  alignas(16) __shared__ char SBl[16384];
  const int t = threadIdx.x;
  const int wave = t>>6, lane = t&63, lg = lane>>4, lr = lane&15;
  const int wm = wave >> 1, wn = wave & 1;
  const int m0 = blockIdx.x*128, n0 = blockIdx.y*128;
  const unsigned short* Ahb = Ah + (size_t)m0*K;
  const unsigned short* Alb = Al + (size_t)m0*K;
  const unsigned short* Bhb = Bh + (size_t)n0*K;
  const unsigned short* Blb = Bl + (size_t)n0*K;
  f4v acc[4][4] = {};
  #pragma unroll 1
  for (int kt = 0; kt < K; kt += 64) {
    __syncthreads();
    #pragma unroll
    for (int i = 0; i < 4; ++i) {
      const size_t go = (size_t)(i*32 + (t>>3))*K + kt + (t&7)*8;
      gld16(Ahb + go, SAh + i*4096 + wave*1024);
      gld16(Alb + go, SAl + i*4096 + wave*1024);
      gld16(Bhb + go, SBh + i*4096 + wave*1024);
      gld16(Blb + go, SBl + i*4096 + wave*1024);
    }
    __syncthreads();
    #pragma unroll
    for (int kk = 0; kk < 2; ++kk) {
      s8v ah[4], al[4], bh[4], bl[4];
      #pragma unroll
      for (int i = 0; i < 4; ++i) {
        const int ro = (wm*64 + i*16 + lr)*128 + kk*64 + lg*16;
        ah[i] = *(const s8v*)&SAh[ro];
        al[i] = *(const s8v*)&SAl[ro];
      }
      #pragma unroll
      for (int j = 0; j < 4; ++j) {
        const int ro = (wn*64 + j*16 + lr)*128 + kk*64 + lg*16;
        bh[j] = *(const s8v*)&SBh[ro];
        bl[j] = *(const s8v*)&SBl[ro];
      }
      #pragma unroll
      for (int i = 0; i < 4; ++i)
        #pragma unroll
        for (int j = 0; j < 4; ++j) {
          f4v a = acc[i][j];
          a = MFMA16(ah[i], bh[j], a);
          a = MFMA16(ah[i], bl[j], a);
          a = MFMA16(al[i], bh[j], a);
          a = MFMA16(al[i], bl[j], a);
          acc[i][j] = a;
        }
    }
  }
  #pragma unroll
  for (int i = 0; i < 4; ++i)
    #pragma unroll
    for (int j = 0; j < 4; ++j) {
      const int row = m0 + wm*64 + i*16 + lg*4;
      const int col = n0 + wn*64 + j*16 + lr;
      #pragma unroll
      for (int r = 0; r < 4; ++r)
        C[(size_t)(row+r)*N + col] = acc[i][j][r];
    }
}

// ---------------- bf16 MFMA GEMM: C = A(bf16)·B(bf16)^T ----------------
template<int BM, int BN, int WN, bool OUTBF>
__global__ __launch_bounds__(256) void gemm_bt(
    const unsigned short* __restrict__ A, const unsigned short* __restrict__ B,
    void* __restrict__ C, int M, int N, int K)
{
  alignas(16) __shared__ char AsB[BM*128];
  alignas(16) __shared__ char BsB[BN*128];
  const int t = threadIdx.x;
  const int wave = t>>6, lane = t&63, lg = lane>>4, lr = lane&15;
  const int wm = wave / WN, wn = wave % WN;
  const int m0 = blockIdx.x*BM, n0 = blockIdx.y*BN;
  const unsigned short* Ab = A + (size_t)m0*K;
  const unsigned short* Bb = B + (size_t)n0*K;
  f4v acc[4][4] = {};
  #pragma unroll 1
  for (int kt = 0; kt < K; kt += 64) {
    __syncthreads();
    #pragma unroll
    for (int i = 0; i < BM/32; ++i)
      gld16(Ab + (size_t)(i*32 + (t>>3))*K + kt + (t&7)*8, AsB + i*4096 + wave*1024);
    #pragma unroll
    for (int i = 0; i < BN/32; ++i)
      gld16(Bb + (size_t)(i*32 + (t>>3))*K + kt + (t&7)*8, BsB + i*4096 + wave*1024);
    __syncthreads();
    #pragma unroll
    for (int kk = 0; kk < 2; ++kk) {
      s8v af[4], bfr[4];
      #pragma unroll
      for (int i = 0; i < 4; ++i)
        af[i] = *(const s8v*)&AsB[(wm*64 + i*16 + lr)*128 + kk*64 + lg*16];
      #pragma unroll
      for (int j = 0; j < 4; ++j)
        bfr[j] = *(const s8v*)&BsB[(wn*64 + j*16 + lr)*128 + kk*64 + lg*16];
      #pragma unroll
      for (int i = 0; i < 4; ++i)
        #pragma unroll
        for (int j = 0; j < 4; ++j)
          acc[i][j] = MFMA16(af[i], bfr[j], acc[i][j]);
    }
  }
  #pragma unroll
  for (int i = 0; i < 4; ++i)
    #pragma unroll
    for (int j = 0; j < 4; ++j) {
      const int row = m0 + wm*64 + i*16 + lg*4;
      const int col = n0 + wn*64 + j*16 + lr;
      #pragma unroll
      for (int r = 0; r < 4; ++r) {
        if (OUTBF) ((unsigned short*)C)[(size_t)(row+r)*N + col] = f2b_rne(acc[i][j][r]);
        else       ((float*)C)[(size_t)(row+r)*N + col] = acc[i][j][r];
      }
    }
}

// ---------------- RoPE f32: Q in-place + bf16 out ----------------
__global__ __launch_bounds__(256) void rope32q_k(float* __restrict__ Qf,
    unsigned short* __restrict__ Qb, const double2* __restrict__ tab){
  const int idx = blockIdx.x*256 + threadIdx.x;
  const int d2 = idx & 31, hh = (idx>>5)&31, s = idx>>10;
  const double2 t = tab[s*32 + d2];
  const float cs = (float)t.x, sn = (float)t.y;
  const size_t base = (size_t)s*2048 + hh*64 + d2;
  const float q1 = Qf[base], q2 = Qf[base+32];
  const float o1 = q1*cs - q2*sn, o2 = q1*sn + q2*cs;
  Qf[base] = o1; Qf[base+32] = o2;
  Qb[base] = f2b_rne(o1); Qb[base+32] = f2b_rne(o2);
}

// ---------------- RoPE f32 on K, write bf16 only ----------------
__global__ __launch_bounds__(256) void rope32_k(const float* __restrict__ Kf,
    unsigned short* __restrict__ Kb, const double2* __restrict__ tab){
  const int idx = blockIdx.x*256 + threadIdx.x;
  const int d2 = idx & 31, hh = (idx>>5)&31, s = idx>>10;
  const double2 t = tab[s*32 + d2];
  const float cs = (float)t.x, sn = (float)t.y;
  const size_t base = (size_t)s*2048 + hh*64 + d2;
  const float k1 = Kf[base], k2 = Kf[base+32];
  Kb[base]    = f2b_rne(k1*cs - k2*sn);
  Kb[base+32] = f2b_rne(k1*sn + k2*cs);
}

// ---------------- V transpose: f32 [S][HD] -> bf16 [HD][S] ----------------
__global__ __launch_bounds__(256) void vtrans_k(const float* __restrict__ V,
                                                unsigned short* __restrict__ Vt){
  __shared__ unsigned short tile[64][68];
  const int s0 = blockIdx.x*64, c0 = blockIdx.y*64;
  const int tx = threadIdx.x & 63, ty = threadIdx.x >> 6;
  #pragma unroll
  for (int rr = 0; rr < 16; ++rr) {
    const int r = ty*16 + rr;
    tile[tx][r] = f2b_rne(V[(size_t)(s0+r)*2048 + c0+tx]);
  }
  __syncthreads();
  #pragma unroll
  for (int rr = 0; rr < 16; ++rr) {
    const int cc = ty*16 + rr;
    Vt[(size_t)(c0+cc)*2048 + s0+tx] = tile[cc][tx];
  }
}

// ---------------- MFMA flash attention: 16 q-rows/wave, K double-buffer pipeline ----
__global__ __launch_bounds__(64) void attn_k(
    const unsigned short* __restrict__ Qb, const unsigned short* __restrict__ Kb,
    const unsigned short* __restrict__ Vt, const float* __restrict__ Gf,
    const unsigned char* __restrict__ Allow, const float* __restrict__ Wn,
    float* __restrict__ Of)
{
  const int h = blockIdx.x, c = blockIdx.y, zb = blockIdx.z;
  const int lane = threadIdx.x, lg = lane>>4, lr = lane&15;
  const int qbase = c*256 + zb*16;
  alignas(16) __shared__ char P[2048];

  const size_t qrow = (size_t)(qbase + lr);
  const s8v qf0 = *(const s8v*)&Qb[qrow*2048 + h*64 + lg*8];
  const s8v qf1 = *(const s8v*)&Qb[qrow*2048 + h*64 + 32 + lg*8];
  const unsigned am = Allow[h*2048 + qrow];
  const int q = qbase + lr;
  const int sw = (lr&7)<<4;

  float mx = -1e30f, ls = 0.f;
  f4v ot[4] = {};

  // active-chunk bitmask (wave-uniform)
  unsigned act = 0;
  for (int n = 0; n <= c; ++n)
    if (__ballot((am>>n)&1u)) act |= (1u<<n);

  auto loadK = [&](s8v (&kf)[4][2], int kb0){
    #pragma unroll
    for (int i = 0; i < 4; ++i) {
      const size_t krow = (size_t)(kb0 + i*16 + lr);
      kf[i][0] = *(const s8v*)&Kb[krow*2048 + h*64 + lg*8];
      kf[i][1] = *(const s8v*)&Kb[krow*2048 + h*64 + 32 + lg*8];
    }
  };

  if (act) {
    int n = (int)__builtin_ctz(act);
    s8v kA[4][2], kB[4][2];
    loadK(kA, n*256);                      // prologue: first K tile
    while (true) {
      const unsigned rem = (n >= 31) ? 0u : (act & ~((2u << n) - 1u));
      const int nnext = rem ? (int)__builtin_ctz(rem) : -1;
      const int okc = (am>>n)&1;
      #pragma unroll
      for (int t4 = 0; t4 < 4; ++t4) {
        const int kb0 = n*256 + t4*64;
        // prefetch next K tile into the other buffer (parity: t4 even uses kA)
        if (t4 < 3) {
          if (t4 & 1) loadK(kA, kb0 + 64);
          else        loadK(kB, kb0 + 64);
        } else if (nnext >= 0) {
          loadK(kA, nnext*256);            // next chunk starts on kA
        }
        // V loads issued early (latency hides under QK^T + softmax)
        s8v vfr[2][4];
        #pragma unroll
        for (int kk = 0; kk < 2; ++kk)
          #pragma unroll
          for (int jd = 0; jd < 4; ++jd)
            vfr[kk][jd] = *(const s8v*)&Vt[(size_t)(h*64 + jd*16 + lr)*2048 + kb0 + kk*32 + lg*8];
        const s8v (*kc)[2] = (t4 & 1) ? kB : kA;
        f4v st[4];
        #pragma unroll
        for (int i = 0; i < 4; ++i) {
          f4v zz = {};
          zz = MFMA16(kc[i][0], qf0, zz);
          st[i] = MFMA16(kc[i][1], qf1, zz);
        }
        float cm = -__builtin_inff();
        #pragma unroll
        for (int i = 0; i < 4; ++i)
          #pragma unroll
          for (int r = 0; r < 4; ++r) {
            float v = st[i][r]*0.125f;
            const int key = kb0 + i*16 + lg*4 + r;
            const bool ok = okc && (n != c || key <= q);
            v = ok ? v : -__builtin_inff();
            st[i][r] = v;
            cm = fmaxf(cm, v);
          }
        cm = fmaxf(cm, __shfl_xor(cm, 16));
        cm = fmaxf(cm, __shfl_xor(cm, 32));
        const float nm = fmaxf(mx, cm);
        const float al = __expf(mx - nm);
        mx = nm;
        float ps = 0.f;
        #pragma unroll
        for (int i = 0; i < 4; ++i) {
          const float p0 = __expf(st[i][0]-mx);
          const float p1 = __expf(st[i][1]-mx);
          const float p2 = __expf(st[i][2]-mx);
          const float p3 = __expf(st[i][3]-mx);
          ps += (p0+p1)+(p2+p3);
          uint2 pk; pk.x = pack2(p0,p1); pk.y = pack2(p2,p3);
          *(uint2*)&P[lr*128 + ((i*32 + lg*8) ^ sw)] = pk;
        }
        ps += __shfl_xor(ps, 16);
        ps += __shfl_xor(ps, 32);
        ls = ls*al + ps;
        #pragma unroll
        for (int jd = 0; jd < 4; ++jd) ot[jd] *= al;
        asm volatile("s_waitcnt lgkmcnt(0)" ::: "memory");
        __builtin_amdgcn_sched_barrier(0);
        #pragma unroll
        for (int kk = 0; kk < 2; ++kk) {
          const s8v pfr = *(const s8v*)&P[lr*128 + ((kk*64 + lg*16) ^ sw)];
          #pragma unroll
          for (int jd = 0; jd < 4; ++jd)
            ot[jd] = MFMA16(vfr[kk][jd], pfr, ot[jd]);
        }
        asm volatile("s_waitcnt lgkmcnt(0)" ::: "memory");
        __builtin_amdgcn_sched_barrier(0);
      }
      if (nnext < 0) break;
      n = nnext;
    }
  }
  const float inv_ = 1.0f/ls;
  float ssum = 0.f;
  #pragma unroll
  for (int jd = 0; jd < 4; ++jd)
    #pragma unroll
    for (int r = 0; r < 4; ++r) {
      const float o = ot[jd][r]*inv_;
      ot[jd][r] = o;
      ssum += o*o;
    }
  ssum += __shfl_xor(ssum, 16);
  ssum += __shfl_xor(ssum, 32);
  const float rmsv = rsqrtf(ssum*(1.0f/64.0f) + 1e-6f);
  #pragma unroll
  for (int jd = 0; jd < 4; ++jd) {
    const float4 w4 = *(const float4*)&Wn[jd*16 + lg*4];
    const float4 g4 = *(const float4*)&Gf[qrow*2048 + h*64 + jd*16 + lg*4];
    float4 o4;
    o4.x = ot[jd][0]*rmsv*w4.x*(1.0f/(1.0f+__expf(-g4.x)));
    o4.y = ot[jd][1]*rmsv*w4.y*(1.0f/(1.0f+__expf(-g4.y)));
    o4.z = ot[jd][2]*rmsv*w4.z*(1.0f/(1.0f+__expf(-g4.z)));
    o4.w = ot[jd][3]*rmsv*w4.w*(1.0f/(1.0f+__expf(-g4.w)));
    *(float4*)&Of[qrow*2048 + h*64 + jd*16 + lg*4] = o4;
  }
}

// ---------------- host launch ----------------
extern "C" void kernel_launch(void* const* d_in, const int* in_sizes, int n_in,
                              void* d_out, int out_size, void* d_ws, size_t ws_size,
                              hipStream_t stream)
{
  const float* hs  = (const float*)d_in[0];
  const float* Wq  = (const float*)d_in[1];
  const float* Wk  = (const float*)d_in[2];
  const float* Wv  = (const float*)d_in[3];
  const float* Wo  = (const float*)d_in[4];
  const float* Wg1 = (const float*)d_in[5];
  const float* Wg2 = (const float*)d_in[6];
  const float* Wn  = (const float*)d_in[7];

  const size_t S2 = (size_t)2048*2048;
  const size_t MB = (size_t)1<<20;
  char* ws = (char*)d_ws;
  // static layout, peak 114MB:
  double2*        tab   = (double2*)       (ws);                   // [0,1)
  unsigned short* Wg1b  = (unsigned short*)(ws + 1*MB);                    // 256KB
  unsigned short* Wg2b  = (unsigned short*)(ws + 1*MB + 262144);          // 256KB
  unsigned short* g1b   = (unsigned short*)(ws + 1*MB + 524288);          // 256KB
  double*         km    = (double*)        (ws + 1*MB + 786432);          // 128KB
  unsigned char*  allow = (unsigned char*) (ws + 1*MB + 917504);          // 64KB
  unsigned char*  flags = (unsigned char*) (ws + 1*MB + 983040);          // 64KB
  unsigned short* hsh   = (unsigned short*)(ws + 2*MB);            // [2,10)
  unsigned short* hsl   = (unsigned short*)(ws + 10*MB);           // [10,18)
  unsigned short* Wqh   = (unsigned short*)(ws + 18*MB);           // [18,26)
  unsigned short* Wql   = (unsigned short*)(ws + 26*MB);           // [26,34)
  unsigned short* Wkh   = (unsigned short*)(ws + 34*MB);           // [34,42)
  unsigned short* Wkl   = (unsigned short*)(ws + 42*MB);           // [42,50)
  unsigned short* Wvb   = (unsigned short*)(ws + 50*MB);           // [50,58)
  float*          qf    = (float*)         (ws + 58*MB);           // [58,74)
  float*          kf    = (float*)         (ws + 74*MB);           // [74,90)
  float*          vf    = (float*)         (ws + 90*MB);           // [90,106)
  double*         Ac    = (double*)        (ws + 106*MB);          // [106,110)
  double*         As    = (double*)        (ws + 110*MB);          // [110,114)
  // phase-2 aliases:
  unsigned short* Ach   = (unsigned short*)(ws + 18*MB);           // dead Wqh [18,19)
  unsigned short* Acl   = (unsigned short*)(ws + 19*MB);           // [19,20)
  unsigned short* Ash   = (unsigned short*)(ws + 20*MB);           // [20,21)
  unsigned short* Asl   = (unsigned short*)(ws + 21*MB);           // [21,22)
  float*          Cc    = (float*)         (ws + 22*MB);           // [22,24)
  float*          Cs    = (float*)         (ws + 24*MB);           // [24,26)
  unsigned short* qb    = (unsigned short*)(ws + 26*MB);           // dead Wql [26,34)
  unsigned short* kb    = (unsigned short*)(ws + 42*MB);           // dead Wkl [42,50)
  unsigned short* vt    = (unsigned short*)(ws + 74*MB);           // dead kf  [74,82)
  unsigned short* ofb   = (unsigned short*)(ws + 82*MB);           // dead kf  [82,90)
  float*          gf    = (float*)         (ws + 90*MB);           // dead vf  [90,106)
  float*          of    = (float*)         (ws + 58*MB);           // dead qf  [58,74)
  unsigned short* Wob   = (unsigned short*)(ws + 106*MB);          // dead Ac/As [106,114)
  (void)ws_size; (void)in_sizes; (void)n_in; (void)out_size;

  rtab_k<<<256,256,0,stream>>>(tab);
  f2bs_k<<<4096,256,0,stream>>>(hs, hsh, hsl, (int)(S2/4));
  f2bs_k<<<4096,256,0,stream>>>(Wq, Wqh, Wql, (int)(S2/4));
  f2bs_k<<<4096,256,0,stream>>>(Wk, Wkh, Wkl, (int)(S2/4));
  f2b4_k<<<4096,256,0,stream>>>(Wv, Wvb, (int)(S2/4));
  f2b4_k<<<128,256,0,stream>>>(Wg1, Wg1b, 64*2048/4);
  f2b4_k<<<128,256,0,stream>>>(Wg2, Wg2b, 2048*64/4);

  // projections (Q f32-exact via 4-term; K,V bf16 — Wkh == f2b4(Wk))
  gemm4_bt<<<dim3(16,16),256,0,stream>>>(hsh, hsl, Wqh, Wql, qf, 2048, 2048, 2048);
  gemm_bt<128,128,2,false><<<dim3(16,16),256,0,stream>>>(hsh, Wkh, kf, 2048, 2048, 2048);
  gemm_bt<128,128,2,false><<<dim3(16,16),256,0,stream>>>(hsh, Wvb, vf, 2048, 2048, 2048);

  // RoPE Q (qb in dead Wql)
  rope32q_k<<<8192,256,0,stream>>>(qf, qb, tab);

  // Km path: wsum -> split-bf16 -> 4-term GEMMs -> combine
  wsum_k<<<dim3(8,32),1024,0,stream>>>(hs, tab, Ac, As);
  d2bs_k<<<1024,256,0,stream>>>(Ac, Ach, Acl, 262144);
  d2bs_k<<<1024,256,0,stream>>>(As, Ash, Asl, 262144);
  gemm4_bt<<<dim3(2,16),256,0,stream>>>(Ach, Acl, Wkh, Wkl, Cc, 256, 2048, 2048);
  gemm4_bt<<<dim3(2,16),256,0,stream>>>(Ash, Asl, Wkh, Wkl, Cs, 256, 2048, 2048);
  kmcomb_k<<<64,256,0,stream>>>(Cc, Cs, km);

  // RoPE K (kb in dead Wkl — after Km gemms)
  rope32_k<<<8192,256,0,stream>>>(kf, kb, tab);

  // selection: gates + margin flags + sparse exact repair
  gate_topk_k<<<dim3(32,8),256,0,stream>>>(qf, km, allow, flags);
  repair_k<<<2048,64,0,stream>>>(hs, Wq, tab, km, flags, allow);

  // V transpose and gate activations (gf in dead vf)
  vtrans_k<<<dim3(32,32),256,0,stream>>>(vf, vt);
  gemm_bt<256,64,1,true><<<dim3(8,1),256,0,stream>>>(hsh, Wg1b, g1b, 2048, 64, 2048);
  gemm_bt<128,128,2,false><<<dim3(16,16),256,0,stream>>>(g1b, Wg2b, gf, 2048, 2048, 64);

  // attention (pipelined)
  attn_k<<<dim3(32,8,16),64,0,stream>>>(qb, kb, vt, gf, allow, Wn, of);

  // output projection -> f32 d_out
  f2b4_k<<<4096,256,0,stream>>>(of, ofb, (int)(S2/4));
  f2b4_k<<<4096,256,0,stream>>>(Wo, Wob, (int)(S2/4));
  gemm_bt<128,128,2,false><<<dim3(16,16),256,0,stream>>>(ofb, Wob, d_out, 2048, 2048, 2048);
}

// Round 17
// 748.384 us; speedup vs baseline: 1.2699x; 1.1186x over previous
//
#include <hip/hip_runtime.h>
#include <hip/hip_bf16.h>

// MoBA attention, MI355X gfx950 — ROUND 17.
// Re-anchor: byte-level R11 (proven 753us: wsum(8,32)+transd+transf+kmean2
// gate path, R11 LDS-P attention) + ONE strictly-safe delta: attn writes bf16
// output directly (same f2b_rne rounding as the deleted f2b4(of) pass).
// Lesson banked: Km-GEMM swap (R15/16) cost ~90us — (2,16) grid = 32 blocks,
// latency-bound; kmean2 is L2-warm-cheap in timed replay despite 872us cold.

typedef __attribute__((ext_vector_type(8))) short s8v;   // 8 x bf16 = 16B
typedef __attribute__((ext_vector_type(4))) float f4v;   // mfma accumulator

#define MFMA16(A,B,C) __builtin_amdgcn_mfma_f32_16x16x32_bf16(A,B,C,0,0,0)

__device__ __forceinline__ unsigned short f2b_rne(float f){
  unsigned u = __builtin_bit_cast(unsigned, f);
  u = (u + 0x7FFFu + ((u>>16)&1u)) >> 16;
  return (unsigned short)u;
}
__device__ __forceinline__ float b2f(unsigned short h){
  unsigned u = ((unsigned)h)<<16;
  return __builtin_bit_cast(float, u);
}
__device__ __forceinline__ unsigned pack2(float a, float b){
  return (unsigned)f2b_rne(a) | ((unsigned)f2b_rne(b)<<16);
}
__device__ __forceinline__ void gld16(const void* g, void* l){
  __builtin_amdgcn_global_load_lds((const __attribute__((address_space(1))) void*)g,
                                   (__attribute__((address_space(3))) void*)l, 16, 0, 0);
}

// ---------------- RoPE table: pure f64 phase ----------------
__global__ __launch_bounds__(256) void rtab_k(double2* __restrict__ tab){
  const int i = blockIdx.x*256 + threadIdx.x;      // 2048*32
  if (i >= 2048*32) return;
  const int d2 = i & 31, s = i >> 5;
  const double invf = 1.0 / pow(10000.0, (double)d2 / 32.0);
  const double ph = (double)s * invf;
  tab[i] = make_double2(cos(ph), sin(ph));
}

// ---------------- f32 -> bf16 convert ----------------
__global__ __launch_bounds__(256) void f2b4_k(const float* __restrict__ s,
                                              unsigned short* __restrict__ d, int n4){
  int i = blockIdx.x*256 + threadIdx.x;
  if (i >= n4) return;
  const float4 v = *(const float4*)(s + (size_t)i*4);
  uint2 p; p.x = pack2(v.x, v.y); p.y = pack2(v.z, v.w);
  *(uint2*)(d + (size_t)i*4) = p;
}

// ---------------- f32 -> bf16 split (hi + lo residual) ----------------
__global__ __launch_bounds__(256) void f2bs_k(const float* __restrict__ s,
    unsigned short* __restrict__ hi, unsigned short* __restrict__ lo, int n4){
  int i = blockIdx.x*256 + threadIdx.x;
  if (i >= n4) return;
  const float4 v = *(const float4*)(s + (size_t)i*4);
  unsigned short h0 = f2b_rne(v.x), h1 = f2b_rne(v.y), h2 = f2b_rne(v.z), h3 = f2b_rne(v.w);
  uint2 ph; ph.x = (unsigned)h0 | ((unsigned)h1<<16); ph.y = (unsigned)h2 | ((unsigned)h3<<16);
  uint2 pl; pl.x = pack2(v.x - b2f(h0), v.y - b2f(h1));
  pl.y = pack2(v.z - b2f(h2), v.w - b2f(h3));
  *(uint2*)(hi + (size_t)i*4) = ph;
  *(uint2*)(lo + (size_t)i*4) = pl;
}

// ---------------- weighted chunk sums (f64): 4 accums, row-major out ----------------
__global__ __launch_bounds__(1024) void wsum_k(const float* __restrict__ hs,
    const double2* __restrict__ tab, double* __restrict__ Ac, double* __restrict__ As){
  const int n = blockIdx.x, d2 = blockIdx.y, tid = threadIdx.x;   // grid (8,32)
  double ac0=0, as0=0, ac1=0, as1=0;
  for (int i = 0; i < 256; ++i) {
    const int s = n*256 + i;
    const double2 t = tab[s*32 + d2];
    const double v0 = (double)hs[(size_t)s*2048 + tid];
    const double v1 = (double)hs[(size_t)s*2048 + tid + 1024];
    ac0 += t.x*v0; as0 += t.y*v0;
    ac1 += t.x*v1; as1 += t.y*v1;
  }
  const size_t ro = (size_t)(n*32 + d2)*2048;
  Ac[ro + tid]      = ac0*(1.0/256.0);
  Ac[ro + tid+1024] = ac1*(1.0/256.0);
  As[ro + tid]      = as0*(1.0/256.0);
  As[ro + tid+1024] = as1*(1.0/256.0);
}

// ---------------- f64 transpose: [R][C] -> [C][R], 64x64 tiles ----------------
__global__ __launch_bounds__(256) void transd_k(const double* __restrict__ in,
    double* __restrict__ out, int R, int C){
  __shared__ double t[64][65];
  const int c0 = blockIdx.x*64, r0 = blockIdx.y*64;
  const int tx = threadIdx.x & 63, ty4 = threadIdx.x >> 6;
  #pragma unroll
  for (int rr = 0; rr < 16; ++rr) {
    const int r = ty4*16 + rr;
    t[r][tx] = in[(size_t)(r0+r)*C + c0+tx];
  }
  __syncthreads();
  #pragma unroll
  for (int rr = 0; rr < 16; ++rr) {
    const int c = ty4*16 + rr;
    out[(size_t)(c0+c)*R + r0+tx] = t[tx][c];
  }
}

// ---------------- f32 transpose: [R][C] -> [C][R], 64x64 tiles ----------------
__global__ __launch_bounds__(256) void transf_k(const float* __restrict__ in,
    float* __restrict__ out, int R, int C){
  __shared__ float t[64][65];
  const int c0 = blockIdx.x*64, r0 = blockIdx.y*64;
  const int tx = threadIdx.x & 63, ty4 = threadIdx.x >> 6;
  #pragma unroll
  for (int rr = 0; rr < 16; ++rr) {
    const int r = ty4*16 + rr;
    t[r][tx] = in[(size_t)(r0+r)*C + c0+tx];
  }
  __syncthreads();
  #pragma unroll
  for (int rr = 0; rr < 16; ++rr) {
    const int c = ty4*16 + rr;
    out[(size_t)(c0+c)*R + r0+tx] = t[tx][c];
  }
}

// ---------------- kmean (f64) from transposed operands, 16-way split-K ----------------
__global__ __launch_bounds__(1024) void kmean2_k(const double* __restrict__ AcT,
    const double* __restrict__ AsT, const float* __restrict__ WkT,
    double* __restrict__ Km){
  const int n = blockIdx.x, h = blockIdx.y;
  const int tid = threadIdx.x, d = tid & 63, p = tid >> 6;   // p in [0,16)
  const int d2 = d & 31;
  const bool hiHalf = d >= 32;
  double a = 0.0, b = 0.0;
  #pragma unroll 4
  for (int c = p*128; c < p*128 + 128; ++c) {
    const double x  = AcT[(size_t)c*256 + n*32 + d2];
    const double y  = AsT[(size_t)c*256 + n*32 + d2];
    const double w1 = (double)WkT[(size_t)c*2048 + h*64 + d2];
    const double w2 = (double)WkT[(size_t)c*2048 + h*64 + d2 + 32];
    if (!hiHalf) { a += x*w1; b += y*w2; }
    else         { a += y*w1; b += x*w2; }
  }
  __shared__ double red[1024];
  red[tid] = hiHalf ? (a + b) : (a - b);
  __syncthreads();
  if (p < 8) red[tid] += red[tid + 512];
  __syncthreads();
  if (p < 4) red[tid] += red[tid + 256];
  __syncthreads();
  if (p < 2) red[tid] += red[tid + 128];
  __syncthreads();
  if (p == 0)
    Km[(size_t)(n*32 + h)*64 + d] = red[d] + red[d + 64];
}

// ---------------- gates from f32 q + f64 km; top-4 + margin flag ----------------
__global__ __launch_bounds__(256) void gate_topk_k(const float* __restrict__ Qf,
    const double* __restrict__ Km, unsigned char* __restrict__ Allow,
    unsigned char* __restrict__ Flags){
  const int h = blockIdx.x, c = blockIdx.y, t = threadIdx.x;
  __shared__ double km[512];
  km[t]     = Km[((t>>6)*32 + h)*64 + (t&63)];
  km[t+256] = Km[(((t+256)>>6)*32 + h)*64 + (t&63)];
  __syncthreads();
  const int s = c*256 + t;
  const float* qp = Qf + (size_t)s*2048 + h*64;
  double g[8] = {};
  for (int d = 0; d < 64; ++d) {
    const double qv = (double)qp[d];
    #pragma unroll
    for (int n2 = 0; n2 < 8; ++n2) g[n2] += qv*km[n2*64+d];
  }
  double margin = 1e300;
  if (c >= 4) {
    unsigned pm = 0;
    double v[4];
    for (int rep = 0; rep < 4; ++rep) {
      double best = -1e308; int bi = 0;
      #pragma unroll
      for (int n2 = 0; n2 < 8; ++n2) {
        const bool take = (n2 < c) && !((pm>>n2)&1u) && (g[n2] > best);
        best = take ? g[n2] : best;
        bi   = take ? n2 : bi;
      }
      v[rep] = best; pm |= 1u<<bi;
    }
    margin = v[2] - v[3];
  }
  Flags[h*2048 + s] = (margin < 1e-3) ? 1 : 0;
  #pragma unroll
  for (int n2 = 0; n2 < 8; ++n2) if (n2 > c) g[n2] = -1e300;
  g[c] = 1e300;
  unsigned mask = 0;
  for (int rep = 0; rep < 4; ++rep) {
    double best = -1e308; int bi = 0;
    #pragma unroll
    for (int n2 = 0; n2 < 8; ++n2) {
      const bool take = !((mask>>n2)&1u) && (g[n2] > best);
      best = take ? g[n2] : best;
      bi   = take ? n2 : bi;
    }
    mask |= 1u<<bi;
  }
  Allow[h*2048 + s] = (unsigned char)mask;
}

// ---------------- sparse f64 repair of flagged rows ----------------
__global__ __launch_bounds__(64) void repair_k(
    const float* __restrict__ hs, const float* __restrict__ Wq,
    const double2* __restrict__ tab, const double* __restrict__ Km,
    const unsigned char* __restrict__ Flags, unsigned char* __restrict__ Allow)
{
  const int s = blockIdx.x, d = threadIdx.x;
  __shared__ double qr[64];
  __shared__ double g8[8];
  for (int h = 0; h < 32; ++h) {
    if (!Flags[h*2048 + s]) continue;
    const float* hrow = hs + (size_t)s*2048;
    const float* wrow = Wq + (size_t)(h*64 + d)*2048;
    double a0=0,a1=0,a2=0,a3=0;
    for (int k = 0; k < 2048; k += 4) {
      a0 += (double)hrow[k]  *(double)wrow[k];
      a1 += (double)hrow[k+1]*(double)wrow[k+1];
      a2 += (double)hrow[k+2]*(double)wrow[k+2];
      a3 += (double)hrow[k+3]*(double)wrow[k+3];
    }
    qr[d] = (a0+a1)+(a2+a3);
    __syncthreads();
    const double2 t = tab[s*32 + (d&31)];
    const double rot = (d < 32) ? (qr[d]*t.x - qr[d+32]*t.y)
                                : (qr[d-32]*t.y + qr[d]*t.x);
    __syncthreads();
    qr[d] = rot;
    __syncthreads();
    if (d < 8) {
      double g = 0;
      const double* kmp = Km + (size_t)(d*32 + h)*64;
      for (int dd = 0; dd < 64; ++dd) g += qr[dd]*kmp[dd];
      g8[d] = g;
    }
    __syncthreads();
    if (d == 0) {
      const int c = s >> 8;
      double g[8];
      #pragma unroll
      for (int n2 = 0; n2 < 8; ++n2)
        g[n2] = (n2 > c) ? -1e300 : ((n2 == c) ? 1e300 : g8[n2]);
      unsigned mask = 0;
      for (int rep = 0; rep < 4; ++rep) {
        double best = -1e308; int bi = 0;
        #pragma unroll
        for (int n2 = 0; n2 < 8; ++n2) {
          const bool take = !((mask>>n2)&1u) && (g[n2] > best);
          best = take ? g[n2] : best;
          bi   = take ? n2 : bi;
        }
        mask |= 1u<<bi;
      }
      Allow[h*2048 + s] = (unsigned char)mask;
    }
    __syncthreads();
  }
}

// ---------------- split-bf16 4-term GEMM (Q only) ----------------
__global__ __launch_bounds__(256) void gemm4_bt(
    const unsigned short* __restrict__ Ah, const unsigned short* __restrict__ Al,
    const unsigned short* __restrict__ Bh, const unsigned short* __restrict__ Bl,
    float* __restrict__ C, int M, int N, int K)
{
  alignas(16) __shared__ char SAh[16384];
  alignas(16) __shared__ char SAl[16384];
  alignas(16) __shared__ char SBh[16384];
  alignas(16) __shared__ char SBl[16384];
  const int t = threadIdx.x;
  const int wave = t>>6, lane = t&63, lg = lane>>4, lr = lane&15;
  const int wm = wave >> 1, wn = wave & 1;
  const int m0 = blockIdx.x*128, n0 = blockIdx.y*128;
  const unsigned short* Ahb = Ah + (size_t)m0*K;
  const unsigned short* Alb = Al + (size_t)m0*K;
  const unsigned short* Bhb = Bh + (size_t)n0*K;
  const unsigned short* Blb = Bl + (size_t)n0*K;
  f4v acc[4][4] = {};
  #pragma unroll 1
  for (int kt = 0; kt < K; kt += 64) {
    __syncthreads();
    #pragma unroll
    for (int i = 0; i < 4; ++i) {
      const size_t go = (size_t)(i*32 + (t>>3))*K + kt + (t&7)*8;
      gld16(Ahb + go, SAh + i*4096 + wave*1024);
      gld16(Alb + go, SAl + i*4096 + wave*1024);
      gld16(Bhb + go, SBh + i*4096 + wave*1024);
      gld16(Blb + go, SBl + i*4096 + wave*1024);
    }
    __syncthreads();
    #pragma unroll
    for (int kk = 0; kk < 2; ++kk) {
      s8v ah[4], al[4], bh[4], bl[4];
      #pragma unroll
      for (int i = 0; i < 4; ++i) {
        const int ro = (wm*64 + i*16 + lr)*128 + kk*64 + lg*16;
        ah[i] = *(const s8v*)&SAh[ro];
        al[i] = *(const s8v*)&SAl[ro];
      }
      #pragma unroll
      for (int j = 0; j < 4; ++j) {
        const int ro = (wn*64 + j*16 + lr)*128 + kk*64 + lg*16;
        bh[j] = *(const s8v*)&SBh[ro];
        bl[j] = *(const s8v*)&SBl[ro];
      }
      #pragma unroll
      for (int i = 0; i < 4; ++i)
        #pragma unroll
        for (int j = 0; j < 4; ++j) {
          f4v a = acc[i][j];
          a = MFMA16(ah[i], bh[j], a);
          a = MFMA16(ah[i], bl[j], a);
          a = MFMA16(al[i], bh[j], a);
          a = MFMA16(al[i], bl[j], a);
          acc[i][j] = a;
        }
    }
  }
  #pragma unroll
  for (int i = 0; i < 4; ++i)
    #pragma unroll
    for (int j = 0; j < 4; ++j) {
      const int row = m0 + wm*64 + i*16 + lg*4;
      const int col = n0 + wn*64 + j*16 + lr;
      #pragma unroll
      for (int r = 0; r < 4; ++r)
        C[(size_t)(row+r)*N + col] = acc[i][j][r];
    }
}

// ---------------- bf16 MFMA GEMM: C = A(bf16)·B(bf16)^T ----------------
template<int BM, int BN, int WN, bool OUTBF>
__global__ __launch_bounds__(256) void gemm_bt(
    const unsigned short* __restrict__ A, const unsigned short* __restrict__ B,
    void* __restrict__ C, int M, int N, int K)
{
  alignas(16) __shared__ char AsB[BM*128];
  alignas(16) __shared__ char BsB[BN*128];
  const int t = threadIdx.x;
  const int wave = t>>6, lane = t&63, lg = lane>>4, lr = lane&15;
  const int wm = wave / WN, wn = wave % WN;
  const int m0 = blockIdx.x*BM, n0 = blockIdx.y*BN;
  const unsigned short* Ab = A + (size_t)m0*K;
  const unsigned short* Bb = B + (size_t)n0*K;
  f4v acc[4][4] = {};
  #pragma unroll 1
  for (int kt = 0; kt < K; kt += 64) {
    __syncthreads();
    #pragma unroll
    for (int i = 0; i < BM/32; ++i)
      gld16(Ab + (size_t)(i*32 + (t>>3))*K + kt + (t&7)*8, AsB + i*4096 + wave*1024);
    #pragma unroll
    for (int i = 0; i < BN/32; ++i)
      gld16(Bb + (size_t)(i*32 + (t>>3))*K + kt + (t&7)*8, BsB + i*4096 + wave*1024);
    __syncthreads();
    #pragma unroll
    for (int kk = 0; kk < 2; ++kk) {
      s8v af[4], bfr[4];
      #pragma unroll
      for (int i = 0; i < 4; ++i)
        af[i] = *(const s8v*)&AsB[(wm*64 + i*16 + lr)*128 + kk*64 + lg*16];
      #pragma unroll
      for (int j = 0; j < 4; ++j)
        bfr[j] = *(const s8v*)&BsB[(wn*64 + j*16 + lr)*128 + kk*64 + lg*16];
      #pragma unroll
      for (int i = 0; i < 4; ++i)
        #pragma unroll
        for (int j = 0; j < 4; ++j)
          acc[i][j] = MFMA16(af[i], bfr[j], acc[i][j]);
    }
  }
  #pragma unroll
  for (int i = 0; i < 4; ++i)
    #pragma unroll
    for (int j = 0; j < 4; ++j) {
      const int row = m0 + wm*64 + i*16 + lg*4;
      const int col = n0 + wn*64 + j*16 + lr;
      #pragma unroll
      for (int r = 0; r < 4; ++r) {
        if (OUTBF) ((unsigned short*)C)[(size_t)(row+r)*N + col] = f2b_rne(acc[i][j][r]);
        else       ((float*)C)[(size_t)(row+r)*N + col] = acc[i][j][r];
      }
    }
}

// ---------------- RoPE f32: Q in-place + bf16 out ----------------
__global__ __launch_bounds__(256) void rope32q_k(float* __restrict__ Qf,
    unsigned short* __restrict__ Qb, const double2* __restrict__ tab){
  const int idx = blockIdx.x*256 + threadIdx.x;
  const int d2 = idx & 31, hh = (idx>>5)&31, s = idx>>10;
  const double2 t = tab[s*32 + d2];
  const float cs = (float)t.x, sn = (float)t.y;
  const size_t base = (size_t)s*2048 + hh*64 + d2;
  const float q1 = Qf[base], q2 = Qf[base+32];
  const float o1 = q1*cs - q2*sn, o2 = q1*sn + q2*cs;
  Qf[base] = o1; Qf[base+32] = o2;
  Qb[base] = f2b_rne(o1); Qb[base+32] = f2b_rne(o2);
}

// ---------------- RoPE f32 on K, write bf16 only ----------------
__global__ __launch_bounds__(256) void rope32_k(const float* __restrict__ Kf,
    unsigned short* __restrict__ Kb, const double2* __restrict__ tab){
  const int idx = blockIdx.x*256 + threadIdx.x;
  const int d2 = idx & 31, hh = (idx>>5)&31, s = idx>>10;
  const double2 t = tab[s*32 + d2];
  const float cs = (float)t.x, sn = (float)t.y;
  const size_t base = (size_t)s*2048 + hh*64 + d2;
  const float k1 = Kf[base], k2 = Kf[base+32];
  Kb[base]    = f2b_rne(k1*cs - k2*sn);
  Kb[base+32] = f2b_rne(k1*sn + k2*cs);
}

// ---------------- V transpose: f32 [S][HD] -> bf16 [HD][S] ----------------
__global__ __launch_bounds__(256) void vtrans_k(const float* __restrict__ V,
                                                unsigned short* __restrict__ Vt){
  __shared__ unsigned short tile[64][68];
  const int s0 = blockIdx.x*64, c0 = blockIdx.y*64;
  const int tx = threadIdx.x & 63, ty = threadIdx.x >> 6;
  #pragma unroll
  for (int rr = 0; rr < 16; ++rr) {
    const int r = ty*16 + rr;
    tile[tx][r] = f2b_rne(V[(size_t)(s0+r)*2048 + c0+tx]);
  }
  __syncthreads();
  #pragma unroll
  for (int rr = 0; rr < 16; ++rr) {
    const int cc = ty*16 + rr;
    Vt[(size_t)(c0+cc)*2048 + s0+tx] = tile[cc][tx];
  }
}

// ---------------- MFMA flash attention: 16 q-rows per wave (R11), bf16 out ----------
__global__ __launch_bounds__(64) void attn_k(
    const unsigned short* __restrict__ Qb, const unsigned short* __restrict__ Kb,
    const unsigned short* __restrict__ Vt, const float* __restrict__ Gf,
    const unsigned char* __restrict__ Allow, const float* __restrict__ Wn,
    unsigned short* __restrict__ Ob)
{
  const int h = blockIdx.x, c = blockIdx.y, zb = blockIdx.z;
  const int lane = threadIdx.x, lg = lane>>4, lr = lane&15;
  const int qbase = c*256 + zb*16;
  alignas(16) __shared__ char P[2048];

  const size_t qrow = (size_t)(qbase + lr);
  const s8v qf0 = *(const s8v*)&Qb[qrow*2048 + h*64 + lg*8];
  const s8v qf1 = *(const s8v*)&Qb[qrow*2048 + h*64 + 32 + lg*8];
  const unsigned am = Allow[h*2048 + qrow];
  const int q = qbase + lr;
  const int sw = (lr&7)<<4;

  float mx = -1e30f, ls = 0.f;
  f4v ot[4] = {};

  for (int n = 0; n <= c; ++n) {
    if (!__ballot((am>>n)&1u)) continue;
    const int okc = (am>>n)&1;
    #pragma unroll 1
    for (int t4 = 0; t4 < 4; ++t4) {
      const int kb0 = n*256 + t4*64;
      s8v kf[4][2];
      #pragma unroll
      for (int i = 0; i < 4; ++i) {
        const size_t krow = (size_t)(kb0 + i*16 + lr);
        kf[i][0] = *(const s8v*)&Kb[krow*2048 + h*64 + lg*8];
        kf[i][1] = *(const s8v*)&Kb[krow*2048 + h*64 + 32 + lg*8];
      }
      f4v st[4];
      #pragma unroll
      for (int i = 0; i < 4; ++i) {
        f4v zz = {};
        zz = MFMA16(kf[i][0], qf0, zz);
        st[i] = MFMA16(kf[i][1], qf1, zz);
      }
      float cm = -__builtin_inff();
      #pragma unroll
      for (int i = 0; i < 4; ++i)
        #pragma unroll
        for (int r = 0; r < 4; ++r) {
          float v = st[i][r]*0.125f;
          const int key = kb0 + i*16 + lg*4 + r;
          const bool ok = okc && (n != c || key <= q);
          v = ok ? v : -__builtin_inff();
          st[i][r] = v;
          cm = fmaxf(cm, v);
        }
      cm = fmaxf(cm, __shfl_xor(cm, 16));
      cm = fmaxf(cm, __shfl_xor(cm, 32));
      const float nm = fmaxf(mx, cm);
      const float al = __expf(mx - nm);
      mx = nm;
      float ps = 0.f;
      #pragma unroll
      for (int i = 0; i < 4; ++i) {
        const float p0 = __expf(st[i][0]-mx);
        const float p1 = __expf(st[i][1]-mx);
        const float p2 = __expf(st[i][2]-mx);
        const float p3 = __expf(st[i][3]-mx);
        ps += (p0+p1)+(p2+p3);
        uint2 pk; pk.x = pack2(p0,p1); pk.y = pack2(p2,p3);
        *(uint2*)&P[lr*128 + ((i*32 + lg*8) ^ sw)] = pk;
      }
      ps += __shfl_xor(ps, 16);
      ps += __shfl_xor(ps, 32);
      ls = ls*al + ps;
      #pragma unroll
      for (int jd = 0; jd < 4; ++jd) ot[jd] *= al;
      asm volatile("s_waitcnt lgkmcnt(0)" ::: "memory");
      __builtin_amdgcn_sched_barrier(0);
      #pragma unroll
      for (int kk = 0; kk < 2; ++kk) {
        s8v vfr[4];
        #pragma unroll
        for (int jd = 0; jd < 4; ++jd)
          vfr[jd] = *(const s8v*)&Vt[(size_t)(h*64 + jd*16 + lr)*2048 + kb0 + kk*32 + lg*8];
        const s8v pfr = *(const s8v*)&P[lr*128 + ((kk*64 + lg*16) ^ sw)];
        #pragma unroll
        for (int jd = 0; jd < 4; ++jd)
          ot[jd] = MFMA16(vfr[jd], pfr, ot[jd]);
      }
      asm volatile("s_waitcnt lgkmcnt(0)" ::: "memory");
      __builtin_amdgcn_sched_barrier(0);
    }
  }
  const float inv_ = 1.0f/ls;
  float ssum = 0.f;
  #pragma unroll
  for (int jd = 0; jd < 4; ++jd)
    #pragma unroll
    for (int r = 0; r < 4; ++r) {
      const float o = ot[jd][r]*inv_;
      ot[jd][r] = o;
      ssum += o*o;
    }
  ssum += __shfl_xor(ssum, 16);
  ssum += __shfl_xor(ssum, 32);
  const float rmsv = rsqrtf(ssum*(1.0f/64.0f) + 1e-6f);
  #pragma unroll
  for (int jd = 0; jd < 4; ++jd) {
    const float4 w4 = *(const float4*)&Wn[jd*16 + lg*4];
    const float4 g4 = *(const float4*)&Gf[qrow*2048 + h*64 + jd*16 + lg*4];
    const float o0 = ot[jd][0]*rmsv*w4.x*(1.0f/(1.0f+__expf(-g4.x)));
    const float o1 = ot[jd][1]*rmsv*w4.y*(1.0f/(1.0f+__expf(-g4.y)));
    const float o2 = ot[jd][2]*rmsv*w4.z*(1.0f/(1.0f+__expf(-g4.z)));
    const float o3 = ot[jd][3]*rmsv*w4.w*(1.0f/(1.0f+__expf(-g4.w)));
    uint2 pk; pk.x = pack2(o0,o1); pk.y = pack2(o2,o3);
    *(uint2*)&Ob[qrow*2048 + h*64 + jd*16 + lg*4] = pk;
  }
}

// ---------------- host launch ----------------
extern "C" void kernel_launch(void* const* d_in, const int* in_sizes, int n_in,
                              void* d_out, int out_size, void* d_ws, size_t ws_size,
                              hipStream_t stream)
{
  const float* hs  = (const float*)d_in[0];
  const float* Wq  = (const float*)d_in[1];
  const float* Wk  = (const float*)d_in[2];
  const float* Wv  = (const float*)d_in[3];
  const float* Wo  = (const float*)d_in[4];
  const float* Wg1 = (const float*)d_in[5];
  const float* Wg2 = (const float*)d_in[6];
  const float* Wn  = (const float*)d_in[7];

  const size_t S2 = (size_t)2048*2048;
  const size_t MB = (size_t)1<<20;
  char* ws = (char*)d_ws;
  // R11 layout, peak 106MB:
  double2*        tab   = (double2*)       (ws);                   // [0,1)
  unsigned short* hsh   = (unsigned short*)(ws + 1*MB);            // [1,9)
  unsigned short* hsl   = (unsigned short*)(ws + 9*MB);            // [9,17)
  unsigned short* Wqh   = (unsigned short*)(ws + 17*MB);           // [17,25)
  unsigned short* Wql   = (unsigned short*)(ws + 25*MB);           // [25,33)
  unsigned short* Wkb   = (unsigned short*)(ws + 33*MB);           // [33,41)
  unsigned short* Wvb   = (unsigned short*)(ws + 41*MB);           // [41,49)
  unsigned short* Wg1b  = (unsigned short*)(ws + 49*MB);                   // 256KB
  unsigned short* Wg2b  = (unsigned short*)(ws + 49*MB + 262144);          // 256KB
  unsigned short* g1b   = (unsigned short*)(ws + 49*MB + 524288);          // 256KB
  double*         km    = (double*)        (ws + 49*MB + 786432);          // 128KB
  unsigned char*  allow = (unsigned char*) (ws + 49*MB + 917504);          // 64KB
  unsigned char*  flags = (unsigned char*) (ws + 49*MB + 983040);          // 64KB
  float*          qf    = (float*)         (ws + 50*MB);           // [50,66)
  float*          kf    = (float*)         (ws + 66*MB);           // [66,82)
  float*          vf    = (float*)         (ws + 82*MB);           // [82,98)
  double*         Ac    = (double*)        (ws + 98*MB);           // [98,102)
  double*         As    = (double*)        (ws + 102*MB);          // [102,106)
  // phase-2 aliases (R11):
  unsigned short* kb    = (unsigned short*)(ws + 17*MB);           // dead Wqh
  unsigned short* qb    = (unsigned short*)(ws + 25*MB);           // dead Wql
  double*         AcT   = (double*)        (ws + 33*MB);           // dead Wkb [33,37)
  double*         AsT   = (double*)        (ws + 37*MB);           // dead Wkb [37,41)
  float*          WkT   = (float*)         (ws + 66*MB);           // dead kf  [66,82)
  unsigned short* vt    = (unsigned short*)(ws + 66*MB);           // post-kmean2 [66,74)
  unsigned short* ob    = (unsigned short*)(ws + 74*MB);           // post-kmean2 [74,82)
  float*          gf    = (float*)         (ws + 82*MB);           // dead vf
  unsigned short* Wob   = (unsigned short*)(ws + 50*MB);           // dead qf [50,58)
  (void)ws_size; (void)in_sizes; (void)n_in; (void)out_size;

  rtab_k<<<256,256,0,stream>>>(tab);
  f2bs_k<<<4096,256,0,stream>>>(hs, hsh, hsl, (int)(S2/4));
  f2bs_k<<<4096,256,0,stream>>>(Wq, Wqh, Wql, (int)(S2/4));
  f2b4_k<<<4096,256,0,stream>>>(Wk, Wkb, (int)(S2/4));
  f2b4_k<<<4096,256,0,stream>>>(Wv, Wvb, (int)(S2/4));
  f2b4_k<<<128,256,0,stream>>>(Wg1, Wg1b, 64*2048/4);
  f2b4_k<<<128,256,0,stream>>>(Wg2, Wg2b, 2048*64/4);

  // projections
  gemm4_bt<<<dim3(16,16),256,0,stream>>>(hsh, hsl, Wqh, Wql, qf, 2048, 2048, 2048);
  gemm_bt<128,128,2,false><<<dim3(16,16),256,0,stream>>>(hsh, Wkb, kf, 2048, 2048, 2048);
  gemm_bt<128,128,2,false><<<dim3(16,16),256,0,stream>>>(hsh, Wvb, vf, 2048, 2048, 2048);

  // RoPE (kf dead after rope32_k)
  rope32q_k<<<8192,256,0,stream>>>(qf, qb, tab);
  rope32_k<<<8192,256,0,stream>>>(kf, kb, tab);

  // exact f64 gate path with transposed kmean operands (R11)
  wsum_k<<<dim3(8,32),1024,0,stream>>>(hs, tab, Ac, As);
  transd_k<<<dim3(32,4),256,0,stream>>>(Ac, AcT, 256, 2048);
  transd_k<<<dim3(32,4),256,0,stream>>>(As, AsT, 256, 2048);
  transf_k<<<dim3(32,32),256,0,stream>>>(Wk, WkT, 2048, 2048);
  kmean2_k<<<dim3(8,32),1024,0,stream>>>(AcT, AsT, WkT, km);
  gate_topk_k<<<dim3(32,8),256,0,stream>>>(qf, km, allow, flags);
  repair_k<<<2048,64,0,stream>>>(hs, Wq, tab, km, flags, allow);

  // V transpose (WkT dead after kmean2) and gate activations
  vtrans_k<<<dim3(32,32),256,0,stream>>>(vf, vt);
  gemm_bt<256,64,1,true><<<dim3(8,1),256,0,stream>>>(hsh, Wg1b, g1b, 2048, 64, 2048);
  gemm_bt<128,128,2,false><<<dim3(16,16),256,0,stream>>>(g1b, Wg2b, gf, 2048, 2048, 64);

  // attention (R11 structure; writes bf16 directly — same rounding as old f2b4 pass)
  attn_k<<<dim3(32,8,16),64,0,stream>>>(qb, kb, vt, gf, allow, Wn, ob);

  // output projection -> f32 d_out
  f2b4_k<<<4096,256,0,stream>>>(Wo, Wob, (int)(S2/4));
  gemm_bt<128,128,2,false><<<dim3(16,16),256,0,stream>>>(ob, Wob, d_out, 2048, 2048, 2048);
}

// Round 18
// 690.282 us; speedup vs baseline: 1.3768x; 1.0842x over previous
//
#include <hip/hip_runtime.h>
#include <hip/hip_bf16.h>

// MoBA attention, MI355X gfx950 — ROUND 18.
// R17 (proven 748us) + fusion pass, math bit-preserved:
//  - K,V projections z-fused into one launch (2 blocks/CU vs 1)
//  - RoPE fused into GEMM epilogues (rotation partners d2/d2+32 are acc[i][j]
//    and acc[i][j+2] in the SAME thread) -> rope32q_k/rope32_k deleted
//  - V written bf16 at the gemm epilogue; vtrans reads bf16 (same rounding pt)

typedef __attribute__((ext_vector_type(8))) short s8v;   // 8 x bf16 = 16B
typedef __attribute__((ext_vector_type(4))) float f4v;   // mfma accumulator

#define MFMA16(A,B,C) __builtin_amdgcn_mfma_f32_16x16x32_bf16(A,B,C,0,0,0)

__device__ __forceinline__ unsigned short f2b_rne(float f){
  unsigned u = __builtin_bit_cast(unsigned, f);
  u = (u + 0x7FFFu + ((u>>16)&1u)) >> 16;
  return (unsigned short)u;
}
__device__ __forceinline__ float b2f(unsigned short h){
  unsigned u = ((unsigned)h)<<16;
  return __builtin_bit_cast(float, u);
}
__device__ __forceinline__ unsigned pack2(float a, float b){
  return (unsigned)f2b_rne(a) | ((unsigned)f2b_rne(b)<<16);
}
__device__ __forceinline__ void gld16(const void* g, void* l){
  __builtin_amdgcn_global_load_lds((const __attribute__((address_space(1))) void*)g,
                                   (__attribute__((address_space(3))) void*)l, 16, 0, 0);
}

// ---------------- RoPE table: pure f64 phase ----------------
__global__ __launch_bounds__(256) void rtab_k(double2* __restrict__ tab){
  const int i = blockIdx.x*256 + threadIdx.x;      // 2048*32
  if (i >= 2048*32) return;
  const int d2 = i & 31, s = i >> 5;
  const double invf = 1.0 / pow(10000.0, (double)d2 / 32.0);
  const double ph = (double)s * invf;
  tab[i] = make_double2(cos(ph), sin(ph));
}

// ---------------- f32 -> bf16 convert ----------------
__global__ __launch_bounds__(256) void f2b4_k(const float* __restrict__ s,
                                              unsigned short* __restrict__ d, int n4){
  int i = blockIdx.x*256 + threadIdx.x;
  if (i >= n4) return;
  const float4 v = *(const float4*)(s + (size_t)i*4);
  uint2 p; p.x = pack2(v.x, v.y); p.y = pack2(v.z, v.w);
  *(uint2*)(d + (size_t)i*4) = p;
}

// ---------------- f32 -> bf16 split (hi + lo residual) ----------------
__global__ __launch_bounds__(256) void f2bs_k(const float* __restrict__ s,
    unsigned short* __restrict__ hi, unsigned short* __restrict__ lo, int n4){
  int i = blockIdx.x*256 + threadIdx.x;
  if (i >= n4) return;
  const float4 v = *(const float4*)(s + (size_t)i*4);
  unsigned short h0 = f2b_rne(v.x), h1 = f2b_rne(v.y), h2 = f2b_rne(v.z), h3 = f2b_rne(v.w);
  uint2 ph; ph.x = (unsigned)h0 | ((unsigned)h1<<16); ph.y = (unsigned)h2 | ((unsigned)h3<<16);
  uint2 pl; pl.x = pack2(v.x - b2f(h0), v.y - b2f(h1));
  pl.y = pack2(v.z - b2f(h2), v.w - b2f(h3));
  *(uint2*)(hi + (size_t)i*4) = ph;
  *(uint2*)(lo + (size_t)i*4) = pl;
}

// ---------------- weighted chunk sums (f64): 4 accums, row-major out ----------------
__global__ __launch_bounds__(1024) void wsum_k(const float* __restrict__ hs,
    const double2* __restrict__ tab, double* __restrict__ Ac, double* __restrict__ As){
  const int n = blockIdx.x, d2 = blockIdx.y, tid = threadIdx.x;   // grid (8,32)
  double ac0=0, as0=0, ac1=0, as1=0;
  for (int i = 0; i < 256; ++i) {
    const int s = n*256 + i;
    const double2 t = tab[s*32 + d2];
    const double v0 = (double)hs[(size_t)s*2048 + tid];
    const double v1 = (double)hs[(size_t)s*2048 + tid + 1024];
    ac0 += t.x*v0; as0 += t.y*v0;
    ac1 += t.x*v1; as1 += t.y*v1;
  }
  const size_t ro = (size_t)(n*32 + d2)*2048;
  Ac[ro + tid]      = ac0*(1.0/256.0);
  Ac[ro + tid+1024] = ac1*(1.0/256.0);
  As[ro + tid]      = as0*(1.0/256.0);
  As[ro + tid+1024] = as1*(1.0/256.0);
}

// ---------------- f64 transpose: [R][C] -> [C][R], 64x64 tiles ----------------
__global__ __launch_bounds__(256) void transd_k(const double* __restrict__ in,
    double* __restrict__ out, int R, int C){
  __shared__ double t[64][65];
  const int c0 = blockIdx.x*64, r0 = blockIdx.y*64;
  const int tx = threadIdx.x & 63, ty4 = threadIdx.x >> 6;
  #pragma unroll
  for (int rr = 0; rr < 16; ++rr) {
    const int r = ty4*16 + rr;
    t[r][tx] = in[(size_t)(r0+r)*C + c0+tx];
  }
  __syncthreads();
  #pragma unroll
  for (int rr = 0; rr < 16; ++rr) {
    const int c = ty4*16 + rr;
    out[(size_t)(c0+c)*R + r0+tx] = t[tx][c];
  }
}

// ---------------- f32 transpose: [R][C] -> [C][R], 64x64 tiles ----------------
__global__ __launch_bounds__(256) void transf_k(const float* __restrict__ in,
    float* __restrict__ out, int R, int C){
  __shared__ float t[64][65];
  const int c0 = blockIdx.x*64, r0 = blockIdx.y*64;
  const int tx = threadIdx.x & 63, ty4 = threadIdx.x >> 6;
  #pragma unroll
  for (int rr = 0; rr < 16; ++rr) {
    const int r = ty4*16 + rr;
    t[r][tx] = in[(size_t)(r0+r)*C + c0+tx];
  }
  __syncthreads();
  #pragma unroll
  for (int rr = 0; rr < 16; ++rr) {
    const int c = ty4*16 + rr;
    out[(size_t)(c0+c)*R + r0+tx] = t[tx][c];
  }
}

// ---------------- kmean (f64) from transposed operands, 16-way split-K ----------------
__global__ __launch_bounds__(1024) void kmean2_k(const double* __restrict__ AcT,
    const double* __restrict__ AsT, const float* __restrict__ WkT,
    double* __restrict__ Km){
  const int n = blockIdx.x, h = blockIdx.y;
  const int tid = threadIdx.x, d = tid & 63, p = tid >> 6;   // p in [0,16)
  const int d2 = d & 31;
  const bool hiHalf = d >= 32;
  double a = 0.0, b = 0.0;
  #pragma unroll 4
  for (int c = p*128; c < p*128 + 128; ++c) {
    const double x  = AcT[(size_t)c*256 + n*32 + d2];
    const double y  = AsT[(size_t)c*256 + n*32 + d2];
    const double w1 = (double)WkT[(size_t)c*2048 + h*64 + d2];
    const double w2 = (double)WkT[(size_t)c*2048 + h*64 + d2 + 32];
    if (!hiHalf) { a += x*w1; b += y*w2; }
    else         { a += y*w1; b += x*w2; }
  }
  __shared__ double red[1024];
  red[tid] = hiHalf ? (a + b) : (a - b);
  __syncthreads();
  if (p < 8) red[tid] += red[tid + 512];
  __syncthreads();
  if (p < 4) red[tid] += red[tid + 256];
  __syncthreads();
  if (p < 2) red[tid] += red[tid + 128];
  __syncthreads();
  if (p == 0)
    Km[(size_t)(n*32 + h)*64 + d] = red[d] + red[d + 64];
}

// ---------------- gates from f32 q + f64 km; top-4 + margin flag ----------------
__global__ __launch_bounds__(256) void gate_topk_k(const float* __restrict__ Qf,
    const double* __restrict__ Km, unsigned char* __restrict__ Allow,
    unsigned char* __restrict__ Flags){
  const int h = blockIdx.x, c = blockIdx.y, t = threadIdx.x;
  __shared__ double km[512];
  km[t]     = Km[((t>>6)*32 + h)*64 + (t&63)];
  km[t+256] = Km[(((t+256)>>6)*32 + h)*64 + (t&63)];
  __syncthreads();
  const int s = c*256 + t;
  const float* qp = Qf + (size_t)s*2048 + h*64;
  double g[8] = {};
  for (int d = 0; d < 64; ++d) {
    const double qv = (double)qp[d];
    #pragma unroll
    for (int n2 = 0; n2 < 8; ++n2) g[n2] += qv*km[n2*64+d];
  }
  double margin = 1e300;
  if (c >= 4) {
    unsigned pm = 0;
    double v[4];
    for (int rep = 0; rep < 4; ++rep) {
      double best = -1e308; int bi = 0;
      #pragma unroll
      for (int n2 = 0; n2 < 8; ++n2) {
        const bool take = (n2 < c) && !((pm>>n2)&1u) && (g[n2] > best);
        best = take ? g[n2] : best;
        bi   = take ? n2 : bi;
      }
      v[rep] = best; pm |= 1u<<bi;
    }
    margin = v[2] - v[3];
  }
  Flags[h*2048 + s] = (margin < 1e-3) ? 1 : 0;
  #pragma unroll
  for (int n2 = 0; n2 < 8; ++n2) if (n2 > c) g[n2] = -1e300;
  g[c] = 1e300;
  unsigned mask = 0;
  for (int rep = 0; rep < 4; ++rep) {
    double best = -1e308; int bi = 0;
    #pragma unroll
    for (int n2 = 0; n2 < 8; ++n2) {
      const bool take = !((mask>>n2)&1u) && (g[n2] > best);
      best = take ? g[n2] : best;
      bi   = take ? n2 : bi;
    }
    mask |= 1u<<bi;
  }
  Allow[h*2048 + s] = (unsigned char)mask;
}

// ---------------- sparse f64 repair of flagged rows ----------------
__global__ __launch_bounds__(64) void repair_k(
    const float* __restrict__ hs, const float* __restrict__ Wq,
    const double2* __restrict__ tab, const double* __restrict__ Km,
    const unsigned char* __restrict__ Flags, unsigned char* __restrict__ Allow)
{
  const int s = blockIdx.x, d = threadIdx.x;
  __shared__ double qr[64];
  __shared__ double g8[8];
  for (int h = 0; h < 32; ++h) {
    if (!Flags[h*2048 + s]) continue;
    const float* hrow = hs + (size_t)s*2048;
    const float* wrow = Wq + (size_t)(h*64 + d)*2048;
    double a0=0,a1=0,a2=0,a3=0;
    for (int k = 0; k < 2048; k += 4) {
      a0 += (double)hrow[k]  *(double)wrow[k];
      a1 += (double)hrow[k+1]*(double)wrow[k+1];
      a2 += (double)hrow[k+2]*(double)wrow[k+2];
      a3 += (double)hrow[k+3]*(double)wrow[k+3];
    }
    qr[d] = (a0+a1)+(a2+a3);
    __syncthreads();
    const double2 t = tab[s*32 + (d&31)];
    const double rot = (d < 32) ? (qr[d]*t.x - qr[d+32]*t.y)
                                : (qr[d-32]*t.y + qr[d]*t.x);
    __syncthreads();
    qr[d] = rot;
    __syncthreads();
    if (d < 8) {
      double g = 0;
      const double* kmp = Km + (size_t)(d*32 + h)*64;
      for (int dd = 0; dd < 64; ++dd) g += qr[dd]*kmp[dd];
      g8[d] = g;
    }
    __syncthreads();
    if (d == 0) {
      const int c = s >> 8;
      double g[8];
      #pragma unroll
      for (int n2 = 0; n2 < 8; ++n2)
        g[n2] = (n2 > c) ? -1e300 : ((n2 == c) ? 1e300 : g8[n2]);
      unsigned mask = 0;
      for (int rep = 0; rep < 4; ++rep) {
        double best = -1e308; int bi = 0;
        #pragma unroll
        for (int n2 = 0; n2 < 8; ++n2) {
          const bool take = !((mask>>n2)&1u) && (g[n2] > best);
          best = take ? g[n2] : best;
          bi   = take ? n2 : bi;
        }
        mask |= 1u<<bi;
      }
      Allow[h*2048 + s] = (unsigned char)mask;
    }
    __syncthreads();
  }
}

// ---------------- split-bf16 4-term GEMM (Q) with fused RoPE epilogue ----------------
// Writes roped qf (f32, for gates) and qb (bf16, for attention).
__global__ __launch_bounds__(256) void gemm4q_k(
    const unsigned short* __restrict__ Ah, const unsigned short* __restrict__ Al,
    const unsigned short* __restrict__ Bh, const unsigned short* __restrict__ Bl,
    const double2* __restrict__ tab,
    float* __restrict__ Qf, unsigned short* __restrict__ Qb, int M, int N, int K)
{
  alignas(16) __shared__ char SAh[16384];
  alignas(16) __shared__ char SAl[16384];
  alignas(16) __shared__ char SBh[16384];
  alignas(16) __shared__ char SBl[16384];
  const int t = threadIdx.x;
  const int wave = t>>6, lane = t&63, lg = lane>>4, lr = lane&15;
  const int wm = wave >> 1, wn = wave & 1;
  const int m0 = blockIdx.x*128, n0 = blockIdx.y*128;
  const unsigned short* Ahb = Ah + (size_t)m0*K;
  const unsigned short* Alb = Al + (size_t)m0*K;
  const unsigned short* Bhb = Bh + (size_t)n0*K;
  const unsigned short* Blb = Bl + (size_t)n0*K;
  f4v acc[4][4] = {};
  #pragma unroll 1
  for (int kt = 0; kt < K; kt += 64) {
    __syncthreads();
    #pragma unroll
    for (int i = 0; i < 4; ++i) {
      const size_t go = (size_t)(i*32 + (t>>3))*K + kt + (t&7)*8;
      gld16(Ahb + go, SAh + i*4096 + wave*1024);
      gld16(Alb + go, SAl + i*4096 + wave*1024);
      gld16(Bhb + go, SBh + i*4096 + wave*1024);
      gld16(Blb + go, SBl + i*4096 + wave*1024);
    }
    __syncthreads();
    #pragma unroll
    for (int kk = 0; kk < 2; ++kk) {
      s8v ah[4], al[4], bh[4], bl[4];
      #pragma unroll
      for (int i = 0; i < 4; ++i) {
        const int ro = (wm*64 + i*16 + lr)*128 + kk*64 + lg*16;
        ah[i] = *(const s8v*)&SAh[ro];
        al[i] = *(const s8v*)&SAl[ro];
      }
      #pragma unroll
      for (int j = 0; j < 4; ++j) {
        const int ro = (wn*64 + j*16 + lr)*128 + kk*64 + lg*16;
        bh[j] = *(const s8v*)&SBh[ro];
        bl[j] = *(const s8v*)&SBl[ro];
      }
      #pragma unroll
      for (int i = 0; i < 4; ++i)
        #pragma unroll
        for (int j = 0; j < 4; ++j) {
          f4v a = acc[i][j];
          a = MFMA16(ah[i], bh[j], a);
          a = MFMA16(ah[i], bl[j], a);
          a = MFMA16(al[i], bh[j], a);
          a = MFMA16(al[i], bl[j], a);
          acc[i][j] = a;
        }
    }
  }
  // fused RoPE epilogue: partners (j, j+2) -> cols d2, d2+32 of the same head
  const int colb = n0 + wn*64;
  #pragma unroll
  for (int i = 0; i < 4; ++i)
    #pragma unroll
    for (int jp = 0; jp < 2; ++jp) {
      const int d2 = jp*16 + lr;
      #pragma unroll
      for (int r = 0; r < 4; ++r) {
        const int row = m0 + wm*64 + i*16 + lg*4 + r;
        const double2 tc = tab[row*32 + d2];
        const float cs = (float)tc.x, sn = (float)tc.y;
        const float q1 = acc[i][jp][r], q2 = acc[i][jp+2][r];
        const float o1 = q1*cs - q2*sn, o2 = q1*sn + q2*cs;
        const size_t base = (size_t)row*N + colb + d2;
        Qf[base]      = o1;  Qf[base+32] = o2;
        Qb[base]      = f2b_rne(o1);
        Qb[base+32]   = f2b_rne(o2);
      }
    }
}

// ---------------- z-fused K/V bf16 GEMM; K gets fused RoPE epilogue ----------------
__global__ __launch_bounds__(256) void gemm_kv_k(
    const unsigned short* __restrict__ A,
    const unsigned short* __restrict__ Bk, const unsigned short* __restrict__ Bv,
    const double2* __restrict__ tab,
    unsigned short* __restrict__ Kb, unsigned short* __restrict__ Vb,
    int M, int N, int K)
{
  alignas(16) __shared__ char AsB[16384];
  alignas(16) __shared__ char BsB[16384];
  const int z = blockIdx.z;
  const unsigned short* B = z ? Bv : Bk;
  const int t = threadIdx.x;
  const int wave = t>>6, lane = t&63, lg = lane>>4, lr = lane&15;
  const int wm = wave >> 1, wn = wave & 1;
  const int m0 = blockIdx.x*128, n0 = blockIdx.y*128;
  const unsigned short* Ab = A + (size_t)m0*K;
  const unsigned short* Bb = B + (size_t)n0*K;
  f4v acc[4][4] = {};
  #pragma unroll 1
  for (int kt = 0; kt < K; kt += 64) {
    __syncthreads();
    #pragma unroll
    for (int i = 0; i < 4; ++i) {
      gld16(Ab + (size_t)(i*32 + (t>>3))*K + kt + (t&7)*8, AsB + i*4096 + wave*1024);
      gld16(Bb + (size_t)(i*32 + (t>>3))*K + kt + (t&7)*8, BsB + i*4096 + wave*1024);
    }
    __syncthreads();
    #pragma unroll
    for (int kk = 0; kk < 2; ++kk) {
      s8v af[4], bfr[4];
      #pragma unroll
      for (int i = 0; i < 4; ++i)
        af[i] = *(const s8v*)&AsB[(wm*64 + i*16 + lr)*128 + kk*64 + lg*16];
      #pragma unroll
      for (int j = 0; j < 4; ++j)
        bfr[j] = *(const s8v*)&BsB[(wn*64 + j*16 + lr)*128 + kk*64 + lg*16];
      #pragma unroll
      for (int i = 0; i < 4; ++i)
        #pragma unroll
        for (int j = 0; j < 4; ++j)
          acc[i][j] = MFMA16(af[i], bfr[j], acc[i][j]);
    }
  }
  const int colb = n0 + wn*64;
  if (z == 0) {
    // K: fused RoPE (partners j, j+2), write bf16
    #pragma unroll
    for (int i = 0; i < 4; ++i)
      #pragma unroll
      for (int jp = 0; jp < 2; ++jp) {
        const int d2 = jp*16 + lr;
        #pragma unroll
        for (int r = 0; r < 4; ++r) {
          const int row = m0 + wm*64 + i*16 + lg*4 + r;
          const double2 tc = tab[row*32 + d2];
          const float cs = (float)tc.x, sn = (float)tc.y;
          const float k1 = acc[i][jp][r], k2 = acc[i][jp+2][r];
          const size_t base = (size_t)row*N + colb + d2;
          Kb[base]    = f2b_rne(k1*cs - k2*sn);
          Kb[base+32] = f2b_rne(k1*sn + k2*cs);
        }
      }
  } else {
    // V: plain bf16 store
    #pragma unroll
    for (int i = 0; i < 4; ++i)
      #pragma unroll
      for (int j = 0; j < 4; ++j) {
        const int col = colb + j*16 + lr;
        const int row0 = m0 + wm*64 + i*16 + lg*4;
        #pragma unroll
        for (int r = 0; r < 4; ++r)
          Vb[(size_t)(row0+r)*N + col] = f2b_rne(acc[i][j][r]);
      }
  }
}

// ---------------- bf16 MFMA GEMM: C = A(bf16)·B(bf16)^T ----------------
template<int BM, int BN, int WN, bool OUTBF>
__global__ __launch_bounds__(256) void gemm_bt(
    const unsigned short* __restrict__ A, const unsigned short* __restrict__ B,
    void* __restrict__ C, int M, int N, int K)
{
  alignas(16) __shared__ char AsB[BM*128];
  alignas(16) __shared__ char BsB[BN*128];
  const int t = threadIdx.x;
  const int wave = t>>6, lane = t&63, lg = lane>>4, lr = lane&15;
  const int wm = wave / WN, wn = wave % WN;
  const int m0 = blockIdx.x*BM, n0 = blockIdx.y*BN;
  const unsigned short* Ab = A + (size_t)m0*K;
  const unsigned short* Bb = B + (size_t)n0*K;
  f4v acc[4][4] = {};
  #pragma unroll 1
  for (int kt = 0; kt < K; kt += 64) {
    __syncthreads();
    #pragma unroll
    for (int i = 0; i < BM/32; ++i)
      gld16(Ab + (size_t)(i*32 + (t>>3))*K + kt + (t&7)*8, AsB + i*4096 + wave*1024);
    #pragma unroll
    for (int i = 0; i < BN/32; ++i)
      gld16(Bb + (size_t)(i*32 + (t>>3))*K + kt + (t&7)*8, BsB + i*4096 + wave*1024);
    __syncthreads();
    #pragma unroll
    for (int kk = 0; kk < 2; ++kk) {
      s8v af[4], bfr[4];
      #pragma unroll
      for (int i = 0; i < 4; ++i)
        af[i] = *(const s8v*)&AsB[(wm*64 + i*16 + lr)*128 + kk*64 + lg*16];
      #pragma unroll
      for (int j = 0; j < 4; ++j)
        bfr[j] = *(const s8v*)&BsB[(wn*64 + j*16 + lr)*128 + kk*64 + lg*16];
      #pragma unroll
      for (int i = 0; i < 4; ++i)
        #pragma unroll
        for (int j = 0; j < 4; ++j)
          acc[i][j] = MFMA16(af[i], bfr[j], acc[i][j]);
    }
  }
  #pragma unroll
  for (int i = 0; i < 4; ++i)
    #pragma unroll
    for (int j = 0; j < 4; ++j) {
      const int row = m0 + wm*64 + i*16 + lg*4;
      const int col = n0 + wn*64 + j*16 + lr;
      #pragma unroll
      for (int r = 0; r < 4; ++r) {
        if (OUTBF) ((unsigned short*)C)[(size_t)(row+r)*N + col] = f2b_rne(acc[i][j][r]);
        else       ((float*)C)[(size_t)(row+r)*N + col] = acc[i][j][r];
      }
    }
}

// ---------------- V transpose: bf16 [S][HD] -> bf16 [HD][S] ----------------
__global__ __launch_bounds__(256) void vtrans_k(const unsigned short* __restrict__ V,
                                                unsigned short* __restrict__ Vt){
  __shared__ unsigned short tile[64][68];
  const int s0 = blockIdx.x*64, c0 = blockIdx.y*64;
  const int tx = threadIdx.x & 63, ty = threadIdx.x >> 6;
  #pragma unroll
  for (int rr = 0; rr < 16; ++rr) {
    const int r = ty*16 + rr;
    tile[tx][r] = V[(size_t)(s0+r)*2048 + c0+tx];
  }
  __syncthreads();
  #pragma unroll
  for (int rr = 0; rr < 16; ++rr) {
    const int cc = ty*16 + rr;
    Vt[(size_t)(c0+cc)*2048 + s0+tx] = tile[cc][tx];
  }
}

// ---------------- MFMA flash attention: 16 q-rows per wave (R11), bf16 out ----------
__global__ __launch_bounds__(64) void attn_k(
    const unsigned short* __restrict__ Qb, const unsigned short* __restrict__ Kb,
    const unsigned short* __restrict__ Vt, const float* __restrict__ Gf,
    const unsigned char* __restrict__ Allow, const float* __restrict__ Wn,
    unsigned short* __restrict__ Ob)
{
  const int h = blockIdx.x, c = blockIdx.y, zb = blockIdx.z;
  const int lane = threadIdx.x, lg = lane>>4, lr = lane&15;
  const int qbase = c*256 + zb*16;
  alignas(16) __shared__ char P[2048];

  const size_t qrow = (size_t)(qbase + lr);
  const s8v qf0 = *(const s8v*)&Qb[qrow*2048 + h*64 + lg*8];
  const s8v qf1 = *(const s8v*)&Qb[qrow*2048 + h*64 + 32 + lg*8];
  const unsigned am = Allow[h*2048 + qrow];
  const int q = qbase + lr;
  const int sw = (lr&7)<<4;

  float mx = -1e30f, ls = 0.f;
  f4v ot[4] = {};

  for (int n = 0; n <= c; ++n) {
    if (!__ballot((am>>n)&1u)) continue;
    const int okc = (am>>n)&1;
    #pragma unroll 1
    for (int t4 = 0; t4 < 4; ++t4) {
      const int kb0 = n*256 + t4*64;
      s8v kf[4][2];
      #pragma unroll
      for (int i = 0; i < 4; ++i) {
        const size_t krow = (size_t)(kb0 + i*16 + lr);
        kf[i][0] = *(const s8v*)&Kb[krow*2048 + h*64 + lg*8];
        kf[i][1] = *(const s8v*)&Kb[krow*2048 + h*64 + 32 + lg*8];
      }
      f4v st[4];
      #pragma unroll
      for (int i = 0; i < 4; ++i) {
        f4v zz = {};
        zz = MFMA16(kf[i][0], qf0, zz);
        st[i] = MFMA16(kf[i][1], qf1, zz);
      }
      float cm = -__builtin_inff();
      #pragma unroll
      for (int i = 0; i < 4; ++i)
        #pragma unroll
        for (int r = 0; r < 4; ++r) {
          float v = st[i][r]*0.125f;
          const int key = kb0 + i*16 + lg*4 + r;
          const bool ok = okc && (n != c || key <= q);
          v = ok ? v : -__builtin_inff();
          st[i][r] = v;
          cm = fmaxf(cm, v);
        }
      cm = fmaxf(cm, __shfl_xor(cm, 16));
      cm = fmaxf(cm, __shfl_xor(cm, 32));
      const float nm = fmaxf(mx, cm);
      const float al = __expf(mx - nm);
      mx = nm;
      float ps = 0.f;
      #pragma unroll
      for (int i = 0; i < 4; ++i) {
        const float p0 = __expf(st[i][0]-mx);
        const float p1 = __expf(st[i][1]-mx);
        const float p2 = __expf(st[i][2]-mx);
        const float p3 = __expf(st[i][3]-mx);
        ps += (p0+p1)+(p2+p3);
        uint2 pk; pk.x = pack2(p0,p1); pk.y = pack2(p2,p3);
        *(uint2*)&P[lr*128 + ((i*32 + lg*8) ^ sw)] = pk;
      }
      ps += __shfl_xor(ps, 16);
      ps += __shfl_xor(ps, 32);
      ls = ls*al + ps;
      #pragma unroll
      for (int jd = 0; jd < 4; ++jd) ot[jd] *= al;
      asm volatile("s_waitcnt lgkmcnt(0)" ::: "memory");
      __builtin_amdgcn_sched_barrier(0);
      #pragma unroll
      for (int kk = 0; kk < 2; ++kk) {
        s8v vfr[4];
        #pragma unroll
        for (int jd = 0; jd < 4; ++jd)
          vfr[jd] = *(const s8v*)&Vt[(size_t)(h*64 + jd*16 + lr)*2048 + kb0 + kk*32 + lg*8];
        const s8v pfr = *(const s8v*)&P[lr*128 + ((kk*64 + lg*16) ^ sw)];
        #pragma unroll
        for (int jd = 0; jd < 4; ++jd)
          ot[jd] = MFMA16(vfr[jd], pfr, ot[jd]);
      }
      asm volatile("s_waitcnt lgkmcnt(0)" ::: "memory");
      __builtin_amdgcn_sched_barrier(0);
    }
  }
  const float inv_ = 1.0f/ls;
  float ssum = 0.f;
  #pragma unroll
  for (int jd = 0; jd < 4; ++jd)
    #pragma unroll
    for (int r = 0; r < 4; ++r) {
      const float o = ot[jd][r]*inv_;
      ot[jd][r] = o;
      ssum += o*o;
    }
  ssum += __shfl_xor(ssum, 16);
  ssum += __shfl_xor(ssum, 32);
  const float rmsv = rsqrtf(ssum*(1.0f/64.0f) + 1e-6f);
  #pragma unroll
  for (int jd = 0; jd < 4; ++jd) {
    const float4 w4 = *(const float4*)&Wn[jd*16 + lg*4];
    const float4 g4 = *(const float4*)&Gf[qrow*2048 + h*64 + jd*16 + lg*4];
    const float o0 = ot[jd][0]*rmsv*w4.x*(1.0f/(1.0f+__expf(-g4.x)));
    const float o1 = ot[jd][1]*rmsv*w4.y*(1.0f/(1.0f+__expf(-g4.y)));
    const float o2 = ot[jd][2]*rmsv*w4.z*(1.0f/(1.0f+__expf(-g4.z)));
    const float o3 = ot[jd][3]*rmsv*w4.w*(1.0f/(1.0f+__expf(-g4.w)));
    uint2 pk; pk.x = pack2(o0,o1); pk.y = pack2(o2,o3);
    *(uint2*)&Ob[qrow*2048 + h*64 + jd*16 + lg*4] = pk;
  }
}

// ---------------- host launch ----------------
extern "C" void kernel_launch(void* const* d_in, const int* in_sizes, int n_in,
                              void* d_out, int out_size, void* d_ws, size_t ws_size,
                              hipStream_t stream)
{
  const float* hs  = (const float*)d_in[0];
  const float* Wq  = (const float*)d_in[1];
  const float* Wk  = (const float*)d_in[2];
  const float* Wv  = (const float*)d_in[3];
  const float* Wo  = (const float*)d_in[4];
  const float* Wg1 = (const float*)d_in[5];
  const float* Wg2 = (const float*)d_in[6];
  const float* Wn  = (const float*)d_in[7];

  const size_t S2 = (size_t)2048*2048;
  const size_t MB = (size_t)1<<20;
  char* ws = (char*)d_ws;
  // layout, peak 114MB (proven):
  double2*        tab   = (double2*)       (ws);                   // [0,1)
  unsigned short* hsh   = (unsigned short*)(ws + 1*MB);            // [1,9)
  unsigned short* hsl   = (unsigned short*)(ws + 9*MB);            // [9,17)
  unsigned short* Wqh   = (unsigned short*)(ws + 17*MB);           // [17,25)
  unsigned short* Wql   = (unsigned short*)(ws + 25*MB);           // [25,33)
  unsigned short* Wkb   = (unsigned short*)(ws + 33*MB);           // [33,41)
  unsigned short* Wvb   = (unsigned short*)(ws + 41*MB);           // [41,49)
  unsigned short* Wg1b  = (unsigned short*)(ws + 49*MB);                   // 256KB
  unsigned short* Wg2b  = (unsigned short*)(ws + 49*MB + 262144);          // 256KB
  unsigned short* g1b   = (unsigned short*)(ws + 49*MB + 524288);          // 256KB
  double*         km    = (double*)        (ws + 49*MB + 786432);          // 128KB
  unsigned char*  allow = (unsigned char*) (ws + 49*MB + 917504);          // 64KB
  unsigned char*  flags = (unsigned char*) (ws + 49*MB + 983040);          // 64KB
  float*          qf    = (float*)         (ws + 50*MB);           // [50,66)
  unsigned short* vb    = (unsigned short*)(ws + 82*MB);           // [82,90) dead after vtrans
  double*         Ac    = (double*)        (ws + 98*MB);           // [98,102)
  double*         As    = (double*)        (ws + 102*MB);          // [102,106)
  unsigned short* qb    = (unsigned short*)(ws + 106*MB);          // [106,114)
  // phase-2 aliases:
  unsigned short* kb    = (unsigned short*)(ws + 17*MB);           // dead Wqh (after gemm4q)
  double*         AcT   = (double*)        (ws + 33*MB);           // dead Wkb [33,37)
  double*         AsT   = (double*)        (ws + 37*MB);           // dead Wkb [37,41)
  float*          WkT   = (float*)         (ws + 66*MB);           // [66,82) free
  unsigned short* vt    = (unsigned short*)(ws + 66*MB);           // post-kmean2 [66,74)
  unsigned short* ob    = (unsigned short*)(ws + 74*MB);           // post-kmean2 [74,82)
  float*          gf    = (float*)         (ws + 82*MB);           // over dead vb [82,98)
  unsigned short* Wob   = (unsigned short*)(ws + 50*MB);           // dead qf [50,58)
  (void)ws_size; (void)in_sizes; (void)n_in; (void)out_size;

  rtab_k<<<256,256,0,stream>>>(tab);
  f2bs_k<<<4096,256,0,stream>>>(hs, hsh, hsl, (int)(S2/4));
  f2bs_k<<<4096,256,0,stream>>>(Wq, Wqh, Wql, (int)(S2/4));
  f2b4_k<<<4096,256,0,stream>>>(Wk, Wkb, (int)(S2/4));
  f2b4_k<<<4096,256,0,stream>>>(Wv, Wvb, (int)(S2/4));
  f2b4_k<<<128,256,0,stream>>>(Wg1, Wg1b, 64*2048/4);
  f2b4_k<<<128,256,0,stream>>>(Wg2, Wg2b, 2048*64/4);

  // Q projection + fused RoPE (writes qf f32 + qb bf16)
  gemm4q_k<<<dim3(16,16),256,0,stream>>>(hsh, hsl, Wqh, Wql, tab, qf, qb, 2048, 2048, 2048);
  // K,V projections z-fused; K gets fused RoPE; both write bf16
  gemm_kv_k<<<dim3(16,16,2),256,0,stream>>>(hsh, Wkb, Wvb, tab, kb, vb, 2048, 2048, 2048);

  // exact f64 gate path with transposed kmean operands (R11)
  wsum_k<<<dim3(8,32),1024,0,stream>>>(hs, tab, Ac, As);
  transd_k<<<dim3(32,4),256,0,stream>>>(Ac, AcT, 256, 2048);
  transd_k<<<dim3(32,4),256,0,stream>>>(As, AsT, 256, 2048);
  transf_k<<<dim3(32,32),256,0,stream>>>(Wk, WkT, 2048, 2048);
  kmean2_k<<<dim3(8,32),1024,0,stream>>>(AcT, AsT, WkT, km);
  gate_topk_k<<<dim3(32,8),256,0,stream>>>(qf, km, allow, flags);
  repair_k<<<2048,64,0,stream>>>(hs, Wq, tab, km, flags, allow);

  // V transpose (WkT dead after kmean2) and gate activations (gf over dead vb)
  vtrans_k<<<dim3(32,32),256,0,stream>>>(vb, vt);
  gemm_bt<256,64,1,true><<<dim3(8,1),256,0,stream>>>(hsh, Wg1b, g1b, 2048, 64, 2048);
  gemm_bt<128,128,2,false><<<dim3(16,16),256,0,stream>>>(g1b, Wg2b, gf, 2048, 2048, 64);

  // attention (R11 structure, bf16 out)
  attn_k<<<dim3(32,8,16),64,0,stream>>>(qb, kb, vt, gf, allow, Wn, ob);

  // output projection -> f32 d_out
  f2b4_k<<<4096,256,0,stream>>>(Wo, Wob, (int)(S2/4));
  gemm_bt<128,128,2,false><<<dim3(16,16),256,0,stream>>>(ob, Wob, d_out, 2048, 2048, 2048);
}